// Round 7
// baseline (3543.660 us; speedup 1.0000x reference)
//
#include <hip/hip_runtime.h>
#include <hip/hip_bf16.h>

typedef __hip_bfloat16 bf16;
using f32x4 = __attribute__((ext_vector_type(4))) float;
using s16x8 = __attribute__((ext_vector_type(8))) short;

#define DEV __device__ __forceinline__
DEV float bf2f(bf16 x) { return __bfloat162float(x); }
DEV bf16  f2bf(float x) { return __float2bfloat16(x); }
DEV ushort f2bu(float x) { bf16 h = __float2bfloat16(x); return *(ushort*)&h; }
DEV float fsig(float x)  { return 1.f / (1.f + __expf(-x)); }
DEV float ftanh(float x) {
    float xc = fminf(fmaxf(x, -15.f), 15.f);
    float e = __expf(2.f * xc);
    return (e - 1.f) / (e + 1.f);
}

#define BB 64
#define SS 256
#define EE 300
#define HH 300
#define H2 600
#define G4 1200
#define RR 512
#define VV 30000

// LSTM-MFMA config: 25 WGs/dir; WG owns 12 h-cols (48 gate rows = 3 n-tiles);
// wave w = m-tile w (16 batch rows) x 3 n-tiles.
// Gates layout is WG-blocked: [t][wg][b][48], col48 = g*12 + j  (6KB/WG/step contig)
#define NWG 25
#define CPW 12      // h-columns per WG  (25*12 = 300)
#define APITCH 328  // LDS A row pitch (ushorts)
#define HPITCH 304  // published-h row pitch (ushorts) = 76 qwords

#define SLOTSZ   19660800ul
#define GATES_SZ 39321600ul
// offsets AFTER the gates region(s); add base2 = conc?GATES_SZ:0
#define OFF_TEXT  39321600ul   // f32 [16384][600]
#define OFF_ADJ   78643200ul   // bf16 [64][256][256]
#define OFF_P     87031808ul   // f32 [1200][46]
#define OFF_DENOM 87252608ul
#define OFF_POSW  87318144ul
#define OFF_L0L1  87383680ul
#define OFF_W1T   87384704ul
#define OFF_W2T   88104704ul
#define OFF_HG    88824704ul   // bf16 [2dirs][2bufs][64][304] = 155648 B
#define OFF_FLAGS 88980352ul   // int  [2][256][32] = 65536 B
#define SEQ_END   89045888ul
#define CONC_END  128367488ul

struct __attribute__((packed, aligned(4))) u16x8v { ushort v[8]; };

// ---------------- small prep kernels ----------------
__global__ void k_init_denom(float* denom) {
    int i = blockIdx.x * 256 + threadIdx.x;
    if (i < BB * SS) denom[i] = 1.f;
}

__global__ void k_lengths(const int* __restrict__ text_idx,
                          const int* __restrict__ aspect_idx,
                          const int* __restrict__ left_idx,
                          int* __restrict__ l0l1, float* __restrict__ posw) {
    int b = blockIdx.x, tid = threadIdx.x;
    __shared__ int cnt[3];
    if (tid < 3) cnt[tid] = 0;
    __syncthreads();
    if (text_idx[b * SS + tid] != 0) atomicAdd(&cnt[0], 1);
    if (tid < 4 && aspect_idx[b * 4 + tid] != 0) atomicAdd(&cnt[1], 1);
    if (tid < 64 && left_idx[b * 64 + tid] != 0) atomicAdd(&cnt[2], 1);
    __syncthreads();
    int tl = cnt[0], al = cnt[1], ll = cnt[2];
    int l0 = ll, l1 = ll + al - 1;
    if (tid == 0) { l0l1[b * 2] = l0; l0l1[b * 2 + 1] = l1; }
    float ctx = fmaxf((float)(tl - al), 1.f);
    float j = (float)tid, l0f = (float)l0, l1f = (float)l1, tlf = (float)tl;
    float w;
    if (j < l0f)       w = 1.f - (l0f - j) / ctx;
    else if (j <= l1f) w = 0.f;
    else if (j < tlf)  w = 1.f - (j - l1f) / ctx;
    else               w = 0.f;
    posw[b * SS + tid] = w;
}

__global__ void k_P(const float* __restrict__ bilW, const float* __restrict__ relE,
                    float* __restrict__ P) {
    int id = blockIdx.x * 256 + threadIdx.x;
    if (id >= G4 * 46) return;
    int i = id / 46, r = id % 46;
    float s = 0.f;
    for (int j = 0; j < 50; ++j) s += bilW[i * 50 + j] * relE[r * 50 + j];
    P[id] = s;
}

__global__ void k_transpose600(const float* __restrict__ W, bf16* __restrict__ WT) {
    int id = blockIdx.x * 256 + threadIdx.x;
    if (id >= H2 * H2) return;
    int n = id / H2, k = id % H2;
    WT[id] = f2bf(W[k * H2 + n]);
}

__global__ void k_pw1(const float* __restrict__ text_out, const float* __restrict__ posw,
                      bf16* __restrict__ pw1) {
    int id = blockIdx.x * 256 + threadIdx.x;
    if (id >= 16384 * H2) return;
    int m = id / H2;
    pw1[id] = f2bf(posw[m] * text_out[id]);
}

// ---------------- MFMA GEMM: C = A * B^T ----------------
// EPI: 0 = +bias0, store bf16 WG-blocked gates: [(t*25+wg)*64+b][48]
//      1 = store bf16 transposed per batch [b][n][j], m=b*256+j
//      2 = v/denom+bias, relu, *posw -> bf16 [grow][ldc]
//      3 = v/denom+bias, relu       -> bf16 [grow][ldc]
template<int EPI, bool GATHER_A, bool BATCHED, bool CVT>
__global__ __launch_bounds__(256) void gemm_bt(
    const void* __restrict__ Abv, const void* __restrict__ Bbv,
    int M, int N, int K, int lda, int ldb, long sA, long sB,
    const int* __restrict__ gidx,
    const float* __restrict__ bias0,
    const float* __restrict__ denom, const float* __restrict__ posw,
    bf16* __restrict__ Cbf, int ldc)
{
    __shared__ __align__(16) ushort As[128 * 40];
    __shared__ __align__(16) ushort Bs[128 * 40];
    const int tid  = threadIdx.x;
    const int lane = tid & 63, wave = tid >> 6;
    const int wm = (wave >> 1) * 64, wn = (wave & 1) * 64;
    const int mt = blockIdx.x * 128, nt = blockIdx.y * 128;
    const int z  = BATCHED ? blockIdx.z : 0;

    const int srow = tid >> 1;
    const int kseg = (tid & 1) * 16;
    long arow = mt + srow;
    if (GATHER_A) {
        int g = gidx[mt + srow];
        if (g < 0 || g >= VV) g = 0;
        arow = g;
    }
    const int nrow = nt + srow;
    const bool bval = nrow < N;
    const int nrc = bval ? nrow : 0;

    const ushort* Ap16 = nullptr; const ushort* Bp16 = nullptr;
    const float*  Ap32 = nullptr; const float*  Bp32 = nullptr;
    if (CVT) {
        Ap32 = (const float*)Abv + (BATCHED ? (long)z * sA : 0l) + arow * (long)lda;
        Bp32 = (const float*)Bbv + (BATCHED ? (long)z * sB : 0l) + (long)nrc * ldb;
    } else {
        Ap16 = (const ushort*)Abv + (BATCHED ? (long)z * sA : 0l) + arow * (long)lda;
        Bp16 = (const ushort*)Bbv + (BATCHED ? (long)z * sB : 0l) + (long)nrc * ldb;
    }

    f32x4 acc[4][4];
#pragma unroll
    for (int i = 0; i < 4; ++i)
#pragma unroll
        for (int j = 0; j < 4; ++j) acc[i][j] = (f32x4){0.f, 0.f, 0.f, 0.f};

    for (int k0 = 0; k0 < K; k0 += 32) {
        __syncthreads();
#pragma unroll
        for (int hv = 0; hv < 2; ++hv) {
            const int kk = k0 + kseg + hv * 8;
            union { ushort u[8]; uint4 q; } ta, tb;
            if (CVT) {
                if (kk + 8 <= K) {
                    float4 f0 = *(const float4*)(Ap32 + kk);
                    float4 f1 = *(const float4*)(Ap32 + kk + 4);
                    ta.u[0] = f2bu(f0.x); ta.u[1] = f2bu(f0.y); ta.u[2] = f2bu(f0.z); ta.u[3] = f2bu(f0.w);
                    ta.u[4] = f2bu(f1.x); ta.u[5] = f2bu(f1.y); ta.u[6] = f2bu(f1.z); ta.u[7] = f2bu(f1.w);
                } else {
#pragma unroll
                    for (int i2 = 0; i2 < 8; ++i2) ta.u[i2] = (kk + i2 < K) ? f2bu(Ap32[kk + i2]) : (ushort)0;
                }
                if (bval && kk + 8 <= K) {
                    float4 f0 = *(const float4*)(Bp32 + kk);
                    float4 f1 = *(const float4*)(Bp32 + kk + 4);
                    tb.u[0] = f2bu(f0.x); tb.u[1] = f2bu(f0.y); tb.u[2] = f2bu(f0.z); tb.u[3] = f2bu(f0.w);
                    tb.u[4] = f2bu(f1.x); tb.u[5] = f2bu(f1.y); tb.u[6] = f2bu(f1.z); tb.u[7] = f2bu(f1.w);
                } else {
#pragma unroll
                    for (int i2 = 0; i2 < 8; ++i2) tb.u[i2] = (bval && kk + i2 < K) ? f2bu(Bp32[kk + i2]) : (ushort)0;
                }
            } else {
                if (kk + 8 <= K) {
                    u16x8v v = *(const u16x8v*)(Ap16 + kk);
#pragma unroll
                    for (int i2 = 0; i2 < 8; ++i2) ta.u[i2] = v.v[i2];
                } else {
#pragma unroll
                    for (int i2 = 0; i2 < 8; ++i2) ta.u[i2] = (kk + i2 < K) ? Ap16[kk + i2] : (ushort)0;
                }
                if (bval && kk + 8 <= K) {
                    u16x8v v = *(const u16x8v*)(Bp16 + kk);
#pragma unroll
                    for (int i2 = 0; i2 < 8; ++i2) tb.u[i2] = v.v[i2];
                } else {
#pragma unroll
                    for (int i2 = 0; i2 < 8; ++i2) tb.u[i2] = (bval && kk + i2 < K) ? Bp16[kk + i2] : (ushort)0;
                }
            }
            *(uint4*)&As[srow * 40 + kseg + hv * 8] = ta.q;
            *(uint4*)&Bs[srow * 40 + kseg + hv * 8] = tb.q;
        }
        __syncthreads();
        s16x8 af[4], bfr[4];
#pragma unroll
        for (int i = 0; i < 4; ++i)
            af[i] = *(const s16x8*)&As[(wm + i * 16 + (lane & 15)) * 40 + (lane >> 4) * 8];
#pragma unroll
        for (int j = 0; j < 4; ++j)
            bfr[j] = *(const s16x8*)&Bs[(wn + j * 16 + (lane & 15)) * 40 + (lane >> 4) * 8];
#pragma unroll
        for (int i = 0; i < 4; ++i)
#pragma unroll
            for (int j = 0; j < 4; ++j)
                acc[i][j] = __builtin_amdgcn_mfma_f32_16x16x32_bf16(af[i], bfr[j], acc[i][j], 0, 0, 0);
    }

#pragma unroll
    for (int i = 0; i < 4; ++i) {
        const int rm = mt + wm + i * 16 + ((lane >> 4) * 4);
#pragma unroll
        for (int j = 0; j < 4; ++j) {
            const int gn = nt + wn + j * 16 + (lane & 15);
            if (gn >= N) continue;
#pragma unroll
            for (int r = 0; r < 4; ++r) {
                const int gm = rm + r;
                const float v = acc[i][j][r];
                if (EPI == 0) {
                    const int bb2 = gm >> 8, tt2 = gm & 255;   // gm = b*SS + t
                    const int g3 = gn / 300, gr = gn % 300;
                    const int wgq = gr / 12, jq = gr % 12;
                    Cbf[(((long)tt2 * NWG + wgq) * BB + bb2) * 48 + g3 * 12 + jq]
                        = f2bf(v + bias0[gn]);
                } else if (EPI == 1) {
                    const int bb2 = gm >> 8, jj = gm & 255;
                    Cbf[((long)bb2 * H2 + gn) * SS + jj] = f2bf(v);
                } else {
                    const int grow = z * SS + gm;
                    float v2 = v / denom[grow] + bias0[gn];
                    v2 = fmaxf(v2, 0.f);
                    if (EPI == 2) v2 *= posw[grow];
                    Cbf[(long)grow * ldc + gn] = f2bf(v2);
                }
            }
        }
    }
}

// ---------------- LSTM recurrence: MFMA, persistent WGs, LLC-direct h, flag barrier --------
// gates WG-blocked: [t][wg][b][48]. h stores/loads agent-scope relaxed atomics
// (LLC-coherent, no L2 flush). text_out plain cacheable stores (read only by
// later kernels; kernel-end writeback suffices). Barrier = per-WG per-step
// flag, release store + parallel relaxed spin on lanes 0..24.
__global__ __launch_bounds__(256, 1) void k_lstm_mfma(
    const bf16* __restrict__ gatesF, const bf16* __restrict__ gatesB,
    const float* __restrict__ WhhF, const float* __restrict__ WhhB,
    bf16* __restrict__ hgbase,   // [2dirs][2bufs][64][HPITCH] zeroed
    int* __restrict__ flagbase,  // [2][256][32] zeroed
    float* __restrict__ text_out, int dir_base)
{
    const int dir = dir_base + blockIdx.x / NWG;
    const int wg  = blockIdx.x % NWG;
    const ushort* gu  = (const ushort*)(dir ? gatesB : gatesF);
    const float*  Whh = dir ? WhhB : WhhF;
    ushort* hg   = (ushort*)hgbase + (long)dir * (2 * 64 * HPITCH);
    int*   flags = flagbase + dir * (256 * 32);

    const int tid = threadIdx.x, lane = tid & 63, wave = tid >> 6;
    __shared__ __align__(16) ushort Alds[64 * APITCH];
    __shared__ float cbuf[64 * CPW];

    const int nl15 = lane & 15;
    const int gI = nl15 & 3;   // gate index: 0=i 1=f 2=g 3=o
    // ---- W_hh slice -> register B-fragments (once) ----
    s16x8 Bfrag[3][10];
#pragma unroll
    for (int tt = 0; tt < 3; ++tt) {
        const int j = (tt * 16 + nl15) >> 2;   // 0..11
        const float* wrow = Whh + ((long)(gI * HH + wg * CPW + j)) * HH;
        const int kb = (lane >> 4) * 8;
        for (int ss = 0; ss < 10; ++ss) {
            union { ushort u[8]; s16x8 v; } tb;
#pragma unroll
            for (int e = 0; e < 8; ++e) {
                const int k = ss * 32 + kb + e;
                tb.u[e] = (k < HH) ? f2bu(wrow[k]) : (ushort)0;
            }
            Bfrag[tt][ss] = tb.v;
        }
    }
    for (int i = tid; i < 64 * CPW; i += 256) cbuf[i] = 0.f;
    for (int i = tid; i < 64 * APITCH; i += 256) Alds[i] = 0;   // pad cols stay 0
    __syncthreads();

    // ---- gate-value register prefetch (step 0); WG-blocked layout ----
    ushort gcur[3][4], gnxt[3][4];
    {
        const int tcur = dir ? (SS - 1) : 0;
#pragma unroll
        for (int tt = 0; tt < 3; ++tt) {
            const int col48 = gI * 12 + ((tt * 16 + nl15) >> 2);
#pragma unroll
            for (int r = 0; r < 4; ++r) {
                const int mb = wave * 16 + ((lane >> 4) << 2) + r;
                gcur[tt][r] = gu[(((long)tcur * NWG + wg) * BB + mb) * 48 + col48];
            }
        }
    }

    for (int s = 0; s < SS; ++s) {
        const int t = dir ? (SS - 1 - s) : s;
        const int rb = s & 1;
        // ---- stage own-wave 16 h-rows from hg[rb] (sc1 8B loads -> LDS) ----
        {
            const unsigned long long* src = (const unsigned long long*)(hg + rb * (64 * HPITCH));
#pragma unroll
            for (int u = 0; u < 19; ++u) {          // 19*64 = 1216 = 16 rows * 76 qwords
                const int i2 = lane + u * 64;
                const int mr = i2 / 76, c4 = i2 % 76;
                const int m = wave * 16 + mr;
                unsigned long long v = __hip_atomic_load(&src[(long)m * 76 + c4],
                                                         __ATOMIC_RELAXED, __HIP_MEMORY_SCOPE_AGENT);
                *(unsigned long long*)&Alds[m * APITCH + c4 * 4] = v;
            }
        }
        // ---- MFMA: C[16 x 48] per wave ----
        f32x4 acc[3];
#pragma unroll
        for (int tt = 0; tt < 3; ++tt) acc[tt] = (f32x4){0.f, 0.f, 0.f, 0.f};
#pragma unroll
        for (int ss = 0; ss < 10; ++ss) {
            s16x8 af = *(const s16x8*)&Alds[(wave * 16 + nl15) * APITCH + ss * 32 + (lane >> 4) * 8];
#pragma unroll
            for (int tt = 0; tt < 3; ++tt)
                acc[tt] = __builtin_amdgcn_mfma_f32_16x16x32_bf16(af, Bfrag[tt][ss], acc[tt], 0, 0, 0);
        }
        // ---- epilogue: activations, c,h update; h via sc1, text_out plain ----
        ushort* hw = hg + (rb ^ 1) * (64 * HPITCH);
#pragma unroll
        for (int tt = 0; tt < 3; ++tt) {
            const int j = (tt * 16 + nl15) >> 2;
            const int hc = wg * CPW + j;
#pragma unroll
            for (int r = 0; r < 4; ++r) {
                const int mb = wave * 16 + ((lane >> 4) << 2) + r;
                const bf16 gb = *(const bf16*)&gcur[tt][r];
                const float val = acc[tt][r] + bf2f(gb);
                const float a = (gI == 2) ? ftanh(val) : fsig(val);
                const float v1 = __shfl_xor(a, 1);
                const float v2 = __shfl_xor(a, 2);
                const float v3 = __shfl_xor(a, 3);
                if (gI == 0) {
                    const int ci = mb * CPW + j;
                    const float c = v1 * cbuf[ci] + a * v2;
                    cbuf[ci] = c;
                    const float h = v3 * ftanh(c);
                    bf16 hb = f2bf(h);
                    __hip_atomic_store(&hw[mb * HPITCH + hc], *(ushort*)&hb,
                                       __ATOMIC_RELAXED, __HIP_MEMORY_SCOPE_AGENT);
                    text_out[((long)(mb * SS + t)) * H2 + dir * HH + hc] = h;
                }
            }
        }
        if (s == SS - 1) break;
        __syncthreads();   // vmcnt(0) before s_barrier => all sc1 stores at LLC
        if (tid == 0)
            __hip_atomic_store(&flags[s * 32 + wg], 1, __ATOMIC_RELEASE, __HIP_MEMORY_SCOPE_AGENT);
        // prefetch next step's gates while waiting (contiguous 6KB/WG block)
        {
            const int tn = dir ? (SS - 2 - s) : (s + 1);
#pragma unroll
            for (int tt = 0; tt < 3; ++tt) {
                const int col48 = gI * 12 + ((tt * 16 + nl15) >> 2);
#pragma unroll
                for (int r = 0; r < 4; ++r) {
                    const int mb = wave * 16 + ((lane >> 4) << 2) + r;
                    gnxt[tt][r] = gu[(((long)tn * NWG + wg) * BB + mb) * 48 + col48];
                }
            }
        }
        if (tid < NWG) {
            while (__hip_atomic_load(&flags[s * 32 + tid], __ATOMIC_RELAXED,
                                     __HIP_MEMORY_SCOPE_AGENT) == 0)
                __builtin_amdgcn_s_sleep(1);
        }
        __syncthreads();
#pragma unroll
        for (int tt = 0; tt < 3; ++tt)
#pragma unroll
            for (int r = 0; r < 4; ++r) gcur[tt][r] = gnxt[tt][r];
    }
}

// ---------------- relation scores -> adj scatter ----------------
__global__ void k_scores(const float* __restrict__ text_out, const float* __restrict__ P,
                         const int* __restrict__ head, const int* __restrict__ behead,
                         const int* __restrict__ rel, const float* __restrict__ bil_b,
                         bf16* __restrict__ adj, float* __restrict__ denom)
{
    const int gw = (blockIdx.x * blockDim.x + threadIdx.x) >> 6;
    const int lane = threadIdx.x & 63;
    if (gw >= BB * RR) return;
    const int b = gw >> 9, r = gw & 511;
    int rl = rel[b * RR + r];     if (rl < 0 || rl > 45) rl = 0;
    int hd = head[b * RR + r]   & 255;
    int bh = behead[b * RR + r] & 255;
    const float* n1 = text_out + ((long)(b * SS + hd)) * H2;
    const float* n2 = text_out + ((long)(b * SS + bh)) * H2;
    float part = 0.f;
    for (int i = lane; i < H2; i += 64) {
        part += n1[i] * P[(long)i * 46 + rl];
        part += n2[i] * P[(long)(H2 + i) * 46 + rl];
    }
    for (int off = 32; off; off >>= 1) part += __shfl_down(part, off);
    if (lane == 0) {
        const float sc = 1.f / (1.f + expf(-(part + bil_b[0])));
        adj[((long)(b * SS + hd)) * SS + bh] = f2bf(sc);
        atomicAdd(&denom[b * SS + hd], sc);
    }
}

// ---------------- pooled attention + FC ----------------
__global__ __launch_bounds__(256) void k_attn(
    const float* __restrict__ text_out, const bf16* __restrict__ x2,
    const int* __restrict__ l0l1, const float* __restrict__ fcW,
    const float* __restrict__ fcb, float* __restrict__ out)
{
    const int b = blockIdx.x, tid = threadIdx.x;
    const int wave = tid >> 6, lane = tid & 63;
    __shared__ float xs[H2];
    __shared__ float sc[SS];
    __shared__ float red[16];
    const int l0 = l0l1[b * 2], l1 = l0l1[b * 2 + 1];
    for (int n = tid; n < H2; n += 256) {
        float s = 0.f;
        for (int i = l0; i <= l1 && i < SS; ++i) s += bf2f(x2[((long)(b * SS + i)) * H2 + n]);
        xs[n] = s;
    }
    __syncthreads();
    for (int j = wave; j < SS; j += 4) {
        const float* row = text_out + ((long)(b * SS + j)) * H2;
        float p = 0.f;
        for (int n = lane; n < H2; n += 64) p += xs[n] * row[n];
        for (int off = 32; off; off >>= 1) p += __shfl_down(p, off);
        if (lane == 0) sc[j] = p;
    }
    __syncthreads();
    const float v = sc[tid];
    float mx = v;
    for (int off = 32; off; off >>= 1) mx = fmaxf(mx, __shfl_down(mx, off));
    if (lane == 0) red[wave] = mx;
    __syncthreads();
    if (tid == 0) red[8] = fmaxf(fmaxf(red[0], red[1]), fmaxf(red[2], red[3]));
    __syncthreads();
    const float e = expf(v - red[8]);
    sc[tid] = e;
    float sm = e;
    for (int off = 32; off; off >>= 1) sm += __shfl_down(sm, off);
    if (lane == 0) red[wave] = sm;
    __syncthreads();
    if (tid == 0) red[9] = red[0] + red[1] + red[2] + red[3];
    __syncthreads();
    const float inv = 1.f / red[9];
    for (int n = tid; n < H2; n += 256) {
        float a = 0.f;
        for (int j = 0; j < SS; ++j) a += sc[j] * text_out[((long)(b * SS + j)) * H2 + n];
        xs[n] = a * inv;
    }
    __syncthreads();
    if (wave < 3) {
        float p = 0.f;
        for (int n = lane; n < H2; n += 64) p += xs[n] * fcW[n * 3 + wave];
        for (int off = 32; off; off >>= 1) p += __shfl_down(p, off);
        if (lane == 0) out[b * 3 + wave] = p + fcb[wave];
    }
}

extern "C" void kernel_launch(void* const* d_in, const int* in_sizes, int n_in,
                              void* d_out, int out_size, void* d_ws, size_t ws_size,
                              hipStream_t stream) {
    const int*   text_idx   = (const int*)d_in[0];
    const int*   aspect_idx = (const int*)d_in[1];
    const int*   left_idx   = (const int*)d_in[2];
    const int*   head       = (const int*)d_in[4];
    const int*   behead     = (const int*)d_in[5];
    const int*   rel        = (const int*)d_in[6];
    const float* embed      = (const float*)d_in[7];
    const float* relE       = (const float*)d_in[8];
    const float* Wf_ih      = (const float*)d_in[9];
    const float* Wf_hh      = (const float*)d_in[10];
    const float* bf_b       = (const float*)d_in[11];
    const float* Wb_ih      = (const float*)d_in[12];
    const float* Wb_hh      = (const float*)d_in[13];
    const float* bb_b       = (const float*)d_in[14];
    const float* bilW       = (const float*)d_in[15];
    const float* bilb       = (const float*)d_in[16];
    const float* gc1W       = (const float*)d_in[17];
    const float* gc1b       = (const float*)d_in[18];
    const float* gc2W       = (const float*)d_in[19];
    const float* gc2b       = (const float*)d_in[20];
    const float* fcW        = (const float*)d_in[21];
    const float* fcb        = (const float*)d_in[22];

    const bool  conc  = ws_size >= CONC_END;
    const size_t base2 = conc ? GATES_SZ : 0ul;

    char* ws = (char*)d_ws;
    bf16*  gatesF   = (bf16*)(ws);
    bf16*  gatesB   = conc ? (bf16*)(ws + GATES_SZ) : gatesF;
    bf16*  slot0bf  = (bf16*)(ws);                 // pw1/pw2/x2 (gates dead after LSTM)
    bf16*  slot1bf  = (bf16*)(ws + SLOTSZ);        // h1T/h2T
    float* text_out = (float*)(ws + OFF_TEXT  + base2);
    bf16*  adjw     = (bf16*)(ws + OFF_ADJ    + base2);
    float* P        = (float*)(ws + OFF_P     + base2);
    float* denom    = (float*)(ws + OFF_DENOM + base2);
    float* posw     = (float*)(ws + OFF_POSW  + base2);
    int*   l0l1     = (int*)(ws + OFF_L0L1    + base2);
    bf16*  W1T      = (bf16*)(ws + OFF_W1T    + base2);
    bf16*  W2T      = (bf16*)(ws + OFF_W2T    + base2);
    bf16*  hgbase   = (bf16*)(ws + OFF_HG     + base2);
    int*   flagbase = (int*)(ws + OFF_FLAGS   + base2);

    dim3 blk(256);

    hipMemsetAsync(adjw, 0, (size_t)BB * SS * SS * 2, stream);
    hipMemsetAsync(hgbase, 0, 155648 + 65536, stream);   // h buffers + flags
    k_init_denom<<<64, blk, 0, stream>>>(denom);
    k_lengths<<<64, blk, 0, stream>>>(text_idx, aspect_idx, left_idx, l0l1, posw);
    k_P<<<(G4 * 46 + 255) / 256, blk, 0, stream>>>(bilW, relE, P);
    k_transpose600<<<(H2 * H2 + 255) / 256, blk, 0, stream>>>(gc1W, W1T);
    k_transpose600<<<(H2 * H2 + 255) / 256, blk, 0, stream>>>(gc2W, W2T);

    if (conc) {
        gemm_bt<0, true, false, true><<<dim3(128, 10), blk, 0, stream>>>(
            embed, Wf_ih, 16384, G4, EE, EE, EE, 0, 0,
            text_idx, bf_b, nullptr, nullptr, gatesF, G4);
        gemm_bt<0, true, false, true><<<dim3(128, 10), blk, 0, stream>>>(
            embed, Wb_ih, 16384, G4, EE, EE, EE, 0, 0,
            text_idx, bb_b, nullptr, nullptr, gatesB, G4);
        k_lstm_mfma<<<2 * NWG, blk, 0, stream>>>(
            gatesF, gatesB, Wf_hh, Wb_hh, hgbase, flagbase, text_out, 0);
    } else {
        gemm_bt<0, true, false, true><<<dim3(128, 10), blk, 0, stream>>>(
            embed, Wf_ih, 16384, G4, EE, EE, EE, 0, 0,
            text_idx, bf_b, nullptr, nullptr, gatesF, G4);
        k_lstm_mfma<<<NWG, blk, 0, stream>>>(
            gatesF, gatesB, Wf_hh, Wb_hh, hgbase, flagbase, text_out, 0);
        gemm_bt<0, true, false, true><<<dim3(128, 10), blk, 0, stream>>>(
            embed, Wb_ih, 16384, G4, EE, EE, EE, 0, 0,
            text_idx, bb_b, nullptr, nullptr, gatesB, G4);
        k_lstm_mfma<<<NWG, blk, 0, stream>>>(
            gatesF, gatesB, Wf_hh, Wb_hh, hgbase, flagbase, text_out, 1);
    }

    k_scores<<<(BB * RR * 64 + 255) / 256, blk, 0, stream>>>(
        text_out, P, head, behead, rel, bilb, adjw, denom);
    k_pw1<<<(16384 * H2 + 255) / 256, blk, 0, stream>>>(text_out, posw, slot0bf);

    gemm_bt<1, false, false, false><<<dim3(128, 5), blk, 0, stream>>>(
        slot0bf, W1T, 16384, H2, H2, H2, H2, 0, 0,
        nullptr, nullptr, nullptr, nullptr, slot1bf, 0);
    gemm_bt<2, false, true, false><<<dim3(2, 5, 64), blk, 0, stream>>>(
        adjw, slot1bf, SS, H2, SS, SS, SS, (long)SS * SS, (long)H2 * SS,
        nullptr, gc1b, denom, posw, slot0bf, H2);
    gemm_bt<1, false, false, false><<<dim3(128, 5), blk, 0, stream>>>(
        slot0bf, W2T, 16384, H2, H2, H2, H2, 0, 0,
        nullptr, nullptr, nullptr, nullptr, slot1bf, 0);
    gemm_bt<3, false, true, false><<<dim3(2, 5, 64), blk, 0, stream>>>(
        adjw, slot1bf, SS, H2, SS, SS, SS, (long)SS * SS, (long)H2 * SS,
        nullptr, gc2b, denom, posw, slot0bf, H2);

    k_attn<<<64, blk, 0, stream>>>(text_out, slot0bf, l0l1, fcW, fcb, (float*)d_out);
}

// Round 8
// 3206.867 us; speedup vs baseline: 1.1050x; 1.1050x over previous
//
#include <hip/hip_runtime.h>
#include <hip/hip_bf16.h>

typedef __hip_bfloat16 bf16;
using f32x4 = __attribute__((ext_vector_type(4))) float;
using s16x8 = __attribute__((ext_vector_type(8))) short;

#define DEV __device__ __forceinline__
DEV float bf2f(bf16 x) { return __bfloat162float(x); }
DEV bf16  f2bf(float x) { return __float2bfloat16(x); }
DEV ushort f2bu(float x) { bf16 h = __float2bfloat16(x); return *(ushort*)&h; }
DEV float fsig(float x)  { return 1.f / (1.f + __expf(-x)); }
DEV float ftanh(float x) {
    float xc = fminf(fmaxf(x, -15.f), 15.f);
    float e = __expf(2.f * xc);
    return (e - 1.f) / (e + 1.f);
}

#define BB 64
#define SS 256
#define EE 300
#define HH 300
#define H2 600
#define G4 1200
#define RR 512
#define VV 30000

// LSTM-MFMA config: 25 WGs/dir; WG owns 12 h-cols (48 gate rows = 3 n-tiles);
// wave w = m-tile w (16 batch rows) x 3 n-tiles.
// Gates layout WG-blocked: [t][wg][b][48], col48 = g*12 + j (6KB/WG/step contig)
#define NWG 25
#define CPW 12      // h-columns per WG  (25*12 = 300)
#define APITCH 328  // LDS A row pitch (ushorts)
#define HPITCH 304  // published-h row pitch (ushorts) = 76 qwords

#define SLOTSZ   19660800ul
#define GATES_SZ 39321600ul
// offsets AFTER the gates region(s); add base2 = conc?GATES_SZ:0
#define OFF_TEXT  39321600ul   // f32 [16384][600]
#define OFF_ADJ   78643200ul   // bf16 [64][256][256]
#define OFF_P     87031808ul   // f32 [1200][46]
#define OFF_DENOM 87252608ul
#define OFF_POSW  87318144ul
#define OFF_L0L1  87383680ul
#define OFF_W1T   87384704ul
#define OFF_W2T   88104704ul
#define OFF_HG    88824704ul   // bf16 [2dirs][2bufs][64][304] = 155648 B
#define OFF_FLAGS 88980352ul   // int  [2][256][32] = 65536 B
#define SEQ_END   89045888ul
#define CONC_END  128367488ul

struct __attribute__((packed, aligned(4))) u16x8v { ushort v[8]; };

// ---------------- small prep kernels ----------------
__global__ void k_init_denom(float* denom) {
    int i = blockIdx.x * 256 + threadIdx.x;
    if (i < BB * SS) denom[i] = 1.f;
}

__global__ void k_lengths(const int* __restrict__ text_idx,
                          const int* __restrict__ aspect_idx,
                          const int* __restrict__ left_idx,
                          int* __restrict__ l0l1, float* __restrict__ posw) {
    int b = blockIdx.x, tid = threadIdx.x;
    __shared__ int cnt[3];
    if (tid < 3) cnt[tid] = 0;
    __syncthreads();
    if (text_idx[b * SS + tid] != 0) atomicAdd(&cnt[0], 1);
    if (tid < 4 && aspect_idx[b * 4 + tid] != 0) atomicAdd(&cnt[1], 1);
    if (tid < 64 && left_idx[b * 64 + tid] != 0) atomicAdd(&cnt[2], 1);
    __syncthreads();
    int tl = cnt[0], al = cnt[1], ll = cnt[2];
    int l0 = ll, l1 = ll + al - 1;
    if (tid == 0) { l0l1[b * 2] = l0; l0l1[b * 2 + 1] = l1; }
    float ctx = fmaxf((float)(tl - al), 1.f);
    float j = (float)tid, l0f = (float)l0, l1f = (float)l1, tlf = (float)tl;
    float w;
    if (j < l0f)       w = 1.f - (l0f - j) / ctx;
    else if (j <= l1f) w = 0.f;
    else if (j < tlf)  w = 1.f - (j - l1f) / ctx;
    else               w = 0.f;
    posw[b * SS + tid] = w;
}

__global__ void k_P(const float* __restrict__ bilW, const float* __restrict__ relE,
                    float* __restrict__ P) {
    int id = blockIdx.x * 256 + threadIdx.x;
    if (id >= G4 * 46) return;
    int i = id / 46, r = id % 46;
    float s = 0.f;
    for (int j = 0; j < 50; ++j) s += bilW[i * 50 + j] * relE[r * 50 + j];
    P[id] = s;
}

__global__ void k_transpose600(const float* __restrict__ W, bf16* __restrict__ WT) {
    int id = blockIdx.x * 256 + threadIdx.x;
    if (id >= H2 * H2) return;
    int n = id / H2, k = id % H2;
    WT[id] = f2bf(W[k * H2 + n]);
}

__global__ void k_pw1(const float* __restrict__ text_out, const float* __restrict__ posw,
                      bf16* __restrict__ pw1) {
    int id = blockIdx.x * 256 + threadIdx.x;
    if (id >= 16384 * H2) return;
    int m = id / H2;
    pw1[id] = f2bf(posw[m] * text_out[id]);
}

// ---------------- MFMA GEMM: C = A * B^T ----------------
// EPI: 0 = +bias0, store bf16 WG-blocked gates: [(t*25+wg)*64+b][48]
//      1 = store bf16 transposed per batch [b][n][j], m=b*256+j
//      2 = v/denom+bias, relu, *posw -> bf16 [grow][ldc]
//      3 = v/denom+bias, relu       -> bf16 [grow][ldc]
template<int EPI, bool GATHER_A, bool BATCHED, bool CVT>
__global__ __launch_bounds__(256) void gemm_bt(
    const void* __restrict__ Abv, const void* __restrict__ Bbv,
    int M, int N, int K, int lda, int ldb, long sA, long sB,
    const int* __restrict__ gidx,
    const float* __restrict__ bias0,
    const float* __restrict__ denom, const float* __restrict__ posw,
    bf16* __restrict__ Cbf, int ldc)
{
    __shared__ __align__(16) ushort As[128 * 40];
    __shared__ __align__(16) ushort Bs[128 * 40];
    const int tid  = threadIdx.x;
    const int lane = tid & 63, wave = tid >> 6;
    const int wm = (wave >> 1) * 64, wn = (wave & 1) * 64;
    const int mt = blockIdx.x * 128, nt = blockIdx.y * 128;
    const int z  = BATCHED ? blockIdx.z : 0;

    const int srow = tid >> 1;
    const int kseg = (tid & 1) * 16;
    long arow = mt + srow;
    if (GATHER_A) {
        int g = gidx[mt + srow];
        if (g < 0 || g >= VV) g = 0;
        arow = g;
    }
    const int nrow = nt + srow;
    const bool bval = nrow < N;
    const int nrc = bval ? nrow : 0;

    const ushort* Ap16 = nullptr; const ushort* Bp16 = nullptr;
    const float*  Ap32 = nullptr; const float*  Bp32 = nullptr;
    if (CVT) {
        Ap32 = (const float*)Abv + (BATCHED ? (long)z * sA : 0l) + arow * (long)lda;
        Bp32 = (const float*)Bbv + (BATCHED ? (long)z * sB : 0l) + (long)nrc * ldb;
    } else {
        Ap16 = (const ushort*)Abv + (BATCHED ? (long)z * sA : 0l) + arow * (long)lda;
        Bp16 = (const ushort*)Bbv + (BATCHED ? (long)z * sB : 0l) + (long)nrc * ldb;
    }

    f32x4 acc[4][4];
#pragma unroll
    for (int i = 0; i < 4; ++i)
#pragma unroll
        for (int j = 0; j < 4; ++j) acc[i][j] = (f32x4){0.f, 0.f, 0.f, 0.f};

    for (int k0 = 0; k0 < K; k0 += 32) {
        __syncthreads();
#pragma unroll
        for (int hv = 0; hv < 2; ++hv) {
            const int kk = k0 + kseg + hv * 8;
            union { ushort u[8]; uint4 q; } ta, tb;
            if (CVT) {
                if (kk + 8 <= K) {
                    float4 f0 = *(const float4*)(Ap32 + kk);
                    float4 f1 = *(const float4*)(Ap32 + kk + 4);
                    ta.u[0] = f2bu(f0.x); ta.u[1] = f2bu(f0.y); ta.u[2] = f2bu(f0.z); ta.u[3] = f2bu(f0.w);
                    ta.u[4] = f2bu(f1.x); ta.u[5] = f2bu(f1.y); ta.u[6] = f2bu(f1.z); ta.u[7] = f2bu(f1.w);
                } else {
#pragma unroll
                    for (int i2 = 0; i2 < 8; ++i2) ta.u[i2] = (kk + i2 < K) ? f2bu(Ap32[kk + i2]) : (ushort)0;
                }
                if (bval && kk + 8 <= K) {
                    float4 f0 = *(const float4*)(Bp32 + kk);
                    float4 f1 = *(const float4*)(Bp32 + kk + 4);
                    tb.u[0] = f2bu(f0.x); tb.u[1] = f2bu(f0.y); tb.u[2] = f2bu(f0.z); tb.u[3] = f2bu(f0.w);
                    tb.u[4] = f2bu(f1.x); tb.u[5] = f2bu(f1.y); tb.u[6] = f2bu(f1.z); tb.u[7] = f2bu(f1.w);
                } else {
#pragma unroll
                    for (int i2 = 0; i2 < 8; ++i2) tb.u[i2] = (bval && kk + i2 < K) ? f2bu(Bp32[kk + i2]) : (ushort)0;
                }
            } else {
                if (kk + 8 <= K) {
                    u16x8v v = *(const u16x8v*)(Ap16 + kk);
#pragma unroll
                    for (int i2 = 0; i2 < 8; ++i2) ta.u[i2] = v.v[i2];
                } else {
#pragma unroll
                    for (int i2 = 0; i2 < 8; ++i2) ta.u[i2] = (kk + i2 < K) ? Ap16[kk + i2] : (ushort)0;
                }
                if (bval && kk + 8 <= K) {
                    u16x8v v = *(const u16x8v*)(Bp16 + kk);
#pragma unroll
                    for (int i2 = 0; i2 < 8; ++i2) tb.u[i2] = v.v[i2];
                } else {
#pragma unroll
                    for (int i2 = 0; i2 < 8; ++i2) tb.u[i2] = (bval && kk + i2 < K) ? Bp16[kk + i2] : (ushort)0;
                }
            }
            *(uint4*)&As[srow * 40 + kseg + hv * 8] = ta.q;
            *(uint4*)&Bs[srow * 40 + kseg + hv * 8] = tb.q;
        }
        __syncthreads();
        s16x8 af[4], bfr[4];
#pragma unroll
        for (int i = 0; i < 4; ++i)
            af[i] = *(const s16x8*)&As[(wm + i * 16 + (lane & 15)) * 40 + (lane >> 4) * 8];
#pragma unroll
        for (int j = 0; j < 4; ++j)
            bfr[j] = *(const s16x8*)&Bs[(wn + j * 16 + (lane & 15)) * 40 + (lane >> 4) * 8];
#pragma unroll
        for (int i = 0; i < 4; ++i)
#pragma unroll
            for (int j = 0; j < 4; ++j)
                acc[i][j] = __builtin_amdgcn_mfma_f32_16x16x32_bf16(af[i], bfr[j], acc[i][j], 0, 0, 0);
    }

#pragma unroll
    for (int i = 0; i < 4; ++i) {
        const int rm = mt + wm + i * 16 + ((lane >> 4) * 4);
#pragma unroll
        for (int j = 0; j < 4; ++j) {
            const int gn = nt + wn + j * 16 + (lane & 15);
            if (gn >= N) continue;
#pragma unroll
            for (int r = 0; r < 4; ++r) {
                const int gm = rm + r;
                const float v = acc[i][j][r];
                if (EPI == 0) {
                    const int bb2 = gm >> 8, tt2 = gm & 255;   // gm = b*SS + t
                    const int g3 = gn / 300, gr = gn % 300;
                    const int wgq = gr / 12, jq = gr % 12;
                    Cbf[(((long)tt2 * NWG + wgq) * BB + bb2) * 48 + g3 * 12 + jq]
                        = f2bf(v + bias0[gn]);
                } else if (EPI == 1) {
                    const int bb2 = gm >> 8, jj = gm & 255;
                    Cbf[((long)bb2 * H2 + gn) * SS + jj] = f2bf(v);
                } else {
                    const int grow = z * SS + gm;
                    float v2 = v / denom[grow] + bias0[gn];
                    v2 = fmaxf(v2, 0.f);
                    if (EPI == 2) v2 *= posw[grow];
                    Cbf[(long)grow * ldc + gn] = f2bf(v2);
                }
            }
        }
    }
}

// ---------------- LSTM recurrence: MFMA, persistent WGs, LLC-direct h, flag barrier --------
// gates WG-blocked: [t][wg][b][48]. h stores/loads agent-scope relaxed atomics
// (sc1 -> LLC coherent, L2 never dirty for h). text_out plain cacheable.
// Barrier: per-WG per-step flag, RELAXED store (no wbl2! __syncthreads drains
// vmcnt(0) => h stores acked at LLC before flag issues) + parallel relaxed
// spin on lanes 0..24.
__global__ __launch_bounds__(256, 1) void k_lstm_mfma(
    const bf16* __restrict__ gatesF, const bf16* __restrict__ gatesB,
    const float* __restrict__ WhhF, const float* __restrict__ WhhB,
    bf16* __restrict__ hgbase,   // [2dirs][2bufs][64][HPITCH] zeroed
    int* __restrict__ flagbase,  // [2][256][32] zeroed
    float* __restrict__ text_out, int dir_base)
{
    const int dir = dir_base + blockIdx.x / NWG;
    const int wg  = blockIdx.x % NWG;
    const ushort* gu  = (const ushort*)(dir ? gatesB : gatesF);
    const float*  Whh = dir ? WhhB : WhhF;
    ushort* hg   = (ushort*)hgbase + (long)dir * (2 * 64 * HPITCH);
    int*   flags = flagbase + dir * (256 * 32);

    const int tid = threadIdx.x, lane = tid & 63, wave = tid >> 6;
    __shared__ __align__(16) ushort Alds[64 * APITCH];
    __shared__ float cbuf[64 * CPW];

    const int nl15 = lane & 15;
    const int gI = nl15 & 3;   // gate index: 0=i 1=f 2=g 3=o
    // ---- W_hh slice -> register B-fragments (once) ----
    s16x8 Bfrag[3][10];
#pragma unroll
    for (int tt = 0; tt < 3; ++tt) {
        const int j = (tt * 16 + nl15) >> 2;   // 0..11
        const float* wrow = Whh + ((long)(gI * HH + wg * CPW + j)) * HH;
        const int kb = (lane >> 4) * 8;
        for (int ss = 0; ss < 10; ++ss) {
            union { ushort u[8]; s16x8 v; } tb;
#pragma unroll
            for (int e = 0; e < 8; ++e) {
                const int k = ss * 32 + kb + e;
                tb.u[e] = (k < HH) ? f2bu(wrow[k]) : (ushort)0;
            }
            Bfrag[tt][ss] = tb.v;
        }
    }
    for (int i = tid; i < 64 * CPW; i += 256) cbuf[i] = 0.f;
    for (int i = tid; i < 64 * APITCH; i += 256) Alds[i] = 0;   // pad cols stay 0
    __syncthreads();

    // ---- gate-value register prefetch (step 0); WG-blocked layout ----
    ushort gcur[3][4], gnxt[3][4];
    {
        const int tcur = dir ? (SS - 1) : 0;
#pragma unroll
        for (int tt = 0; tt < 3; ++tt) {
            const int col48 = gI * 12 + ((tt * 16 + nl15) >> 2);
#pragma unroll
            for (int r = 0; r < 4; ++r) {
                const int mb = wave * 16 + ((lane >> 4) << 2) + r;
                gcur[tt][r] = gu[(((long)tcur * NWG + wg) * BB + mb) * 48 + col48];
            }
        }
    }

    for (int s = 0; s < SS; ++s) {
        const int t = dir ? (SS - 1 - s) : s;
        const int rb = s & 1;
        // ---- stage own-wave 16 h-rows from hg[rb] (sc1 8B loads -> LDS) ----
        {
            const unsigned long long* src = (const unsigned long long*)(hg + rb * (64 * HPITCH));
#pragma unroll
            for (int u = 0; u < 19; ++u) {          // 19*64 = 1216 = 16 rows * 76 qwords
                const int i2 = lane + u * 64;
                const int mr = i2 / 76, c4 = i2 % 76;
                const int m = wave * 16 + mr;
                unsigned long long v = __hip_atomic_load(&src[(long)m * 76 + c4],
                                                         __ATOMIC_RELAXED, __HIP_MEMORY_SCOPE_AGENT);
                *(unsigned long long*)&Alds[m * APITCH + c4 * 4] = v;
            }
        }
        // ---- MFMA: C[16 x 48] per wave ----
        f32x4 acc[3];
#pragma unroll
        for (int tt = 0; tt < 3; ++tt) acc[tt] = (f32x4){0.f, 0.f, 0.f, 0.f};
#pragma unroll
        for (int ss = 0; ss < 10; ++ss) {
            s16x8 af = *(const s16x8*)&Alds[(wave * 16 + nl15) * APITCH + ss * 32 + (lane >> 4) * 8];
#pragma unroll
            for (int tt = 0; tt < 3; ++tt)
                acc[tt] = __builtin_amdgcn_mfma_f32_16x16x32_bf16(af, Bfrag[tt][ss], acc[tt], 0, 0, 0);
        }
        // ---- epilogue: activations, c,h update; h via sc1, text_out plain ----
        ushort* hw = hg + (rb ^ 1) * (64 * HPITCH);
#pragma unroll
        for (int tt = 0; tt < 3; ++tt) {
            const int j = (tt * 16 + nl15) >> 2;
            const int hc = wg * CPW + j;
#pragma unroll
            for (int r = 0; r < 4; ++r) {
                const int mb = wave * 16 + ((lane >> 4) << 2) + r;
                const bf16 gb = *(const bf16*)&gcur[tt][r];
                const float val = acc[tt][r] + bf2f(gb);
                const float a = (gI == 2) ? ftanh(val) : fsig(val);
                const float v1 = __shfl_xor(a, 1);
                const float v2 = __shfl_xor(a, 2);
                const float v3 = __shfl_xor(a, 3);
                if (gI == 0) {
                    const int ci = mb * CPW + j;
                    const float c = v1 * cbuf[ci] + a * v2;
                    cbuf[ci] = c;
                    const float h = v3 * ftanh(c);
                    bf16 hb = f2bf(h);
                    __hip_atomic_store(&hw[mb * HPITCH + hc], *(ushort*)&hb,
                                       __ATOMIC_RELAXED, __HIP_MEMORY_SCOPE_AGENT);
                    text_out[((long)(mb * SS + t)) * H2 + dir * HH + hc] = h;
                }
            }
        }
        if (s == SS - 1) break;
        __syncthreads();   // s_waitcnt vmcnt(0) + s_barrier => h stores acked at LLC
        if (tid == 0)
            __hip_atomic_store(&flags[s * 32 + wg], 1, __ATOMIC_RELAXED, __HIP_MEMORY_SCOPE_AGENT);
        // prefetch next step's gates while waiting (contiguous 6KB/WG block)
        {
            const int tn = dir ? (SS - 2 - s) : (s + 1);
#pragma unroll
            for (int tt = 0; tt < 3; ++tt) {
                const int col48 = gI * 12 + ((tt * 16 + nl15) >> 2);
#pragma unroll
                for (int r = 0; r < 4; ++r) {
                    const int mb = wave * 16 + ((lane >> 4) << 2) + r;
                    gnxt[tt][r] = gu[(((long)tn * NWG + wg) * BB + mb) * 48 + col48];
                }
            }
        }
        if (tid < NWG) {
            while (__hip_atomic_load(&flags[s * 32 + tid], __ATOMIC_RELAXED,
                                     __HIP_MEMORY_SCOPE_AGENT) == 0)
                __builtin_amdgcn_s_sleep(1);
        }
        __syncthreads();
#pragma unroll
        for (int tt = 0; tt < 3; ++tt)
#pragma unroll
            for (int r = 0; r < 4; ++r) gcur[tt][r] = gnxt[tt][r];
    }
}

// ---------------- relation scores -> adj scatter ----------------
__global__ void k_scores(const float* __restrict__ text_out, const float* __restrict__ P,
                         const int* __restrict__ head, const int* __restrict__ behead,
                         const int* __restrict__ rel, const float* __restrict__ bil_b,
                         bf16* __restrict__ adj, float* __restrict__ denom)
{
    const int gw = (blockIdx.x * blockDim.x + threadIdx.x) >> 6;
    const int lane = threadIdx.x & 63;
    if (gw >= BB * RR) return;
    const int b = gw >> 9, r = gw & 511;
    int rl = rel[b * RR + r];     if (rl < 0 || rl > 45) rl = 0;
    int hd = head[b * RR + r]   & 255;
    int bh = behead[b * RR + r] & 255;
    const float* n1 = text_out + ((long)(b * SS + hd)) * H2;
    const float* n2 = text_out + ((long)(b * SS + bh)) * H2;
    float part = 0.f;
    for (int i = lane; i < H2; i += 64) {
        part += n1[i] * P[(long)i * 46 + rl];
        part += n2[i] * P[(long)(H2 + i) * 46 + rl];
    }
    for (int off = 32; off; off >>= 1) part += __shfl_down(part, off);
    if (lane == 0) {
        const float sc = 1.f / (1.f + expf(-(part + bil_b[0])));
        adj[((long)(b * SS + hd)) * SS + bh] = f2bf(sc);
        atomicAdd(&denom[b * SS + hd], sc);
    }
}

// ---------------- pooled attention + FC ----------------
__global__ __launch_bounds__(256) void k_attn(
    const float* __restrict__ text_out, const bf16* __restrict__ x2,
    const int* __restrict__ l0l1, const float* __restrict__ fcW,
    const float* __restrict__ fcb, float* __restrict__ out)
{
    const int b = blockIdx.x, tid = threadIdx.x;
    const int wave = tid >> 6, lane = tid & 63;
    __shared__ float xs[H2];
    __shared__ float sc[SS];
    __shared__ float red[16];
    const int l0 = l0l1[b * 2], l1 = l0l1[b * 2 + 1];
    for (int n = tid; n < H2; n += 256) {
        float s = 0.f;
        for (int i = l0; i <= l1 && i < SS; ++i) s += bf2f(x2[((long)(b * SS + i)) * H2 + n]);
        xs[n] = s;
    }
    __syncthreads();
    for (int j = wave; j < SS; j += 4) {
        const float* row = text_out + ((long)(b * SS + j)) * H2;
        float p = 0.f;
        for (int n = lane; n < H2; n += 64) p += xs[n] * row[n];
        for (int off = 32; off; off >>= 1) p += __shfl_down(p, off);
        if (lane == 0) sc[j] = p;
    }
    __syncthreads();
    const float v = sc[tid];
    float mx = v;
    for (int off = 32; off; off >>= 1) mx = fmaxf(mx, __shfl_down(mx, off));
    if (lane == 0) red[wave] = mx;
    __syncthreads();
    if (tid == 0) red[8] = fmaxf(fmaxf(red[0], red[1]), fmaxf(red[2], red[3]));
    __syncthreads();
    const float e = expf(v - red[8]);
    sc[tid] = e;
    float sm = e;
    for (int off = 32; off; off >>= 1) sm += __shfl_down(sm, off);
    if (lane == 0) red[wave] = sm;
    __syncthreads();
    if (tid == 0) red[9] = red[0] + red[1] + red[2] + red[3];
    __syncthreads();
    const float inv = 1.f / red[9];
    for (int n = tid; n < H2; n += 256) {
        float a = 0.f;
        for (int j = 0; j < SS; ++j) a += sc[j] * text_out[((long)(b * SS + j)) * H2 + n];
        xs[n] = a * inv;
    }
    __syncthreads();
    if (wave < 3) {
        float p = 0.f;
        for (int n = lane; n < H2; n += 64) p += xs[n] * fcW[n * 3 + wave];
        for (int off = 32; off; off >>= 1) p += __shfl_down(p, off);
        if (lane == 0) out[b * 3 + wave] = p + fcb[wave];
    }
}

extern "C" void kernel_launch(void* const* d_in, const int* in_sizes, int n_in,
                              void* d_out, int out_size, void* d_ws, size_t ws_size,
                              hipStream_t stream) {
    const int*   text_idx   = (const int*)d_in[0];
    const int*   aspect_idx = (const int*)d_in[1];
    const int*   left_idx   = (const int*)d_in[2];
    const int*   head       = (const int*)d_in[4];
    const int*   behead     = (const int*)d_in[5];
    const int*   rel        = (const int*)d_in[6];
    const float* embed      = (const float*)d_in[7];
    const float* relE       = (const float*)d_in[8];
    const float* Wf_ih      = (const float*)d_in[9];
    const float* Wf_hh      = (const float*)d_in[10];
    const float* bf_b       = (const float*)d_in[11];
    const float* Wb_ih      = (const float*)d_in[12];
    const float* Wb_hh      = (const float*)d_in[13];
    const float* bb_b       = (const float*)d_in[14];
    const float* bilW       = (const float*)d_in[15];
    const float* bilb       = (const float*)d_in[16];
    const float* gc1W       = (const float*)d_in[17];
    const float* gc1b       = (const float*)d_in[18];
    const float* gc2W       = (const float*)d_in[19];
    const float* gc2b       = (const float*)d_in[20];
    const float* fcW        = (const float*)d_in[21];
    const float* fcb        = (const float*)d_in[22];

    const bool  conc  = ws_size >= CONC_END;
    const size_t base2 = conc ? GATES_SZ : 0ul;

    char* ws = (char*)d_ws;
    bf16*  gatesF   = (bf16*)(ws);
    bf16*  gatesB   = conc ? (bf16*)(ws + GATES_SZ) : gatesF;
    bf16*  slot0bf  = (bf16*)(ws);                 // pw1/pw2/x2 (gates dead after LSTM)
    bf16*  slot1bf  = (bf16*)(ws + SLOTSZ);        // h1T/h2T
    float* text_out = (float*)(ws + OFF_TEXT  + base2);
    bf16*  adjw     = (bf16*)(ws + OFF_ADJ    + base2);
    float* P        = (float*)(ws + OFF_P     + base2);
    float* denom    = (float*)(ws + OFF_DENOM + base2);
    float* posw     = (float*)(ws + OFF_POSW  + base2);
    int*   l0l1     = (int*)(ws + OFF_L0L1    + base2);
    bf16*  W1T      = (bf16*)(ws + OFF_W1T    + base2);
    bf16*  W2T      = (bf16*)(ws + OFF_W2T    + base2);
    bf16*  hgbase   = (bf16*)(ws + OFF_HG     + base2);
    int*   flagbase = (int*)(ws + OFF_FLAGS   + base2);

    dim3 blk(256);

    hipMemsetAsync(adjw, 0, (size_t)BB * SS * SS * 2, stream);
    hipMemsetAsync(hgbase, 0, 155648 + 65536, stream);   // h buffers + flags
    k_init_denom<<<64, blk, 0, stream>>>(denom);
    k_lengths<<<64, blk, 0, stream>>>(text_idx, aspect_idx, left_idx, l0l1, posw);
    k_P<<<(G4 * 46 + 255) / 256, blk, 0, stream>>>(bilW, relE, P);
    k_transpose600<<<(H2 * H2 + 255) / 256, blk, 0, stream>>>(gc1W, W1T);
    k_transpose600<<<(H2 * H2 + 255) / 256, blk, 0, stream>>>(gc2W, W2T);

    if (conc) {
        gemm_bt<0, true, false, true><<<dim3(128, 10), blk, 0, stream>>>(
            embed, Wf_ih, 16384, G4, EE, EE, EE, 0, 0,
            text_idx, bf_b, nullptr, nullptr, gatesF, G4);
        gemm_bt<0, true, false, true><<<dim3(128, 10), blk, 0, stream>>>(
            embed, Wb_ih, 16384, G4, EE, EE, EE, 0, 0,
            text_idx, bb_b, nullptr, nullptr, gatesB, G4);
        k_lstm_mfma<<<2 * NWG, blk, 0, stream>>>(
            gatesF, gatesB, Wf_hh, Wb_hh, hgbase, flagbase, text_out, 0);
    } else {
        gemm_bt<0, true, false, true><<<dim3(128, 10), blk, 0, stream>>>(
            embed, Wf_ih, 16384, G4, EE, EE, EE, 0, 0,
            text_idx, bf_b, nullptr, nullptr, gatesF, G4);
        k_lstm_mfma<<<NWG, blk, 0, stream>>>(
            gatesF, gatesB, Wf_hh, Wb_hh, hgbase, flagbase, text_out, 0);
        gemm_bt<0, true, false, true><<<dim3(128, 10), blk, 0, stream>>>(
            embed, Wb_ih, 16384, G4, EE, EE, EE, 0, 0,
            text_idx, bb_b, nullptr, nullptr, gatesB, G4);
        k_lstm_mfma<<<NWG, blk, 0, stream>>>(
            gatesF, gatesB, Wf_hh, Wb_hh, hgbase, flagbase, text_out, 1);
    }

    k_scores<<<(BB * RR * 64 + 255) / 256, blk, 0, stream>>>(
        text_out, P, head, behead, rel, bilb, adjw, denom);
    k_pw1<<<(16384 * H2 + 255) / 256, blk, 0, stream>>>(text_out, posw, slot0bf);

    gemm_bt<1, false, false, false><<<dim3(128, 5), blk, 0, stream>>>(
        slot0bf, W1T, 16384, H2, H2, H2, H2, 0, 0,
        nullptr, nullptr, nullptr, nullptr, slot1bf, 0);
    gemm_bt<2, false, true, false><<<dim3(2, 5, 64), blk, 0, stream>>>(
        adjw, slot1bf, SS, H2, SS, SS, SS, (long)SS * SS, (long)H2 * SS,
        nullptr, gc1b, denom, posw, slot0bf, H2);
    gemm_bt<1, false, false, false><<<dim3(128, 5), blk, 0, stream>>>(
        slot0bf, W2T, 16384, H2, H2, H2, H2, 0, 0,
        nullptr, nullptr, nullptr, nullptr, slot1bf, 0);
    gemm_bt<3, false, true, false><<<dim3(2, 5, 64), blk, 0, stream>>>(
        adjw, slot1bf, SS, H2, SS, SS, SS, (long)SS * SS, (long)H2 * SS,
        nullptr, gc2b, denom, posw, slot0bf, H2);

    k_attn<<<64, blk, 0, stream>>>(text_out, slot0bf, l0l1, fcW, fcb, (float*)d_out);
}

// Round 9
// 2086.751 us; speedup vs baseline: 1.6982x; 1.5368x over previous
//
#include <hip/hip_runtime.h>
#include <hip/hip_bf16.h>

typedef __hip_bfloat16 bf16;
using f32x4 = __attribute__((ext_vector_type(4))) float;
using s16x8 = __attribute__((ext_vector_type(8))) short;

#define DEV __device__ __forceinline__
DEV float bf2f(bf16 x) { return __bfloat162float(x); }
DEV bf16  f2bf(float x) { return __float2bfloat16(x); }
DEV ushort f2bu(float x) { bf16 h = __float2bfloat16(x); return *(ushort*)&h; }
DEV float fsig(float x)  { return 1.f / (1.f + __expf(-x)); }
DEV float ftanh(float x) {
    float xc = fminf(fmaxf(x, -15.f), 15.f);
    float e = __expf(2.f * xc);
    return (e - 1.f) / (e + 1.f);
}

#define BB 64
#define SS 256
#define EE 300
#define HH 300
#define H2 600
#define G4 1200
#define RR 512
#define VV 30000

// LSTM-MFMA config: 25 WGs/dir; WG owns 12 h-cols (48 gate rows = 3 n-tiles);
// wave w = m-tile w (16 batch rows) x 3 n-tiles.
// Gates WG-blocked: [t][wg][b][48], col48 = g*12+j. h exchanged via LLC (sc1),
// A-fragments loaded DIRECTLY global->registers (20 parallel 8B loads, no LDS).
#define NWG 25
#define CPW 12      // h-columns per WG  (25*12 = 300)
#define HPITCH 304  // published-h row pitch (ushorts) = 76 qwords

#define SLOTSZ   19660800ul
#define GATES_SZ 39321600ul
// offsets AFTER the gates region(s); add base2 = conc?GATES_SZ:0
#define OFF_TEXT  39321600ul   // f32 [16384][600]
#define OFF_ADJ   78643200ul   // bf16 [64][256][256]
#define OFF_P     87031808ul   // f32 [1200][46]
#define OFF_DENOM 87252608ul
#define OFF_POSW  87318144ul
#define OFF_L0L1  87383680ul
#define OFF_W1T   87384704ul
#define OFF_W2T   88104704ul
#define OFF_HG    88824704ul   // bf16 [2dirs][2bufs][64][304] = 155648 B
#define OFF_FLAGS 88980352ul   // int  [2][256][32] = 65536 B
#define SEQ_END   89045888ul
#define CONC_END  128367488ul

struct __attribute__((packed, aligned(4))) u16x8v { ushort v[8]; };

// ---------------- small prep kernels ----------------
__global__ void k_init_denom(float* denom) {
    int i = blockIdx.x * 256 + threadIdx.x;
    if (i < BB * SS) denom[i] = 1.f;
}

__global__ void k_lengths(const int* __restrict__ text_idx,
                          const int* __restrict__ aspect_idx,
                          const int* __restrict__ left_idx,
                          int* __restrict__ l0l1, float* __restrict__ posw) {
    int b = blockIdx.x, tid = threadIdx.x;
    __shared__ int cnt[3];
    if (tid < 3) cnt[tid] = 0;
    __syncthreads();
    if (text_idx[b * SS + tid] != 0) atomicAdd(&cnt[0], 1);
    if (tid < 4 && aspect_idx[b * 4 + tid] != 0) atomicAdd(&cnt[1], 1);
    if (tid < 64 && left_idx[b * 64 + tid] != 0) atomicAdd(&cnt[2], 1);
    __syncthreads();
    int tl = cnt[0], al = cnt[1], ll = cnt[2];
    int l0 = ll, l1 = ll + al - 1;
    if (tid == 0) { l0l1[b * 2] = l0; l0l1[b * 2 + 1] = l1; }
    float ctx = fmaxf((float)(tl - al), 1.f);
    float j = (float)tid, l0f = (float)l0, l1f = (float)l1, tlf = (float)tl;
    float w;
    if (j < l0f)       w = 1.f - (l0f - j) / ctx;
    else if (j <= l1f) w = 0.f;
    else if (j < tlf)  w = 1.f - (j - l1f) / ctx;
    else               w = 0.f;
    posw[b * SS + tid] = w;
}

__global__ void k_P(const float* __restrict__ bilW, const float* __restrict__ relE,
                    float* __restrict__ P) {
    int id = blockIdx.x * 256 + threadIdx.x;
    if (id >= G4 * 46) return;
    int i = id / 46, r = id % 46;
    float s = 0.f;
    for (int j = 0; j < 50; ++j) s += bilW[i * 50 + j] * relE[r * 50 + j];
    P[id] = s;
}

__global__ void k_transpose600(const float* __restrict__ W, bf16* __restrict__ WT) {
    int id = blockIdx.x * 256 + threadIdx.x;
    if (id >= H2 * H2) return;
    int n = id / H2, k = id % H2;
    WT[id] = f2bf(W[k * H2 + n]);
}

__global__ void k_pw1(const float* __restrict__ text_out, const float* __restrict__ posw,
                      bf16* __restrict__ pw1) {
    int id = blockIdx.x * 256 + threadIdx.x;
    if (id >= 16384 * H2) return;
    int m = id / H2;
    pw1[id] = f2bf(posw[m] * text_out[id]);
}

// ---------------- MFMA GEMM: C = A * B^T ----------------
// EPI: 0 = +bias0, store bf16 WG-blocked gates: [(t*25+wg)*64+b][48]
//      1 = store bf16 transposed per batch [b][n][j], m=b*256+j
//      2 = v/denom+bias, relu, *posw -> bf16 [grow][ldc]
//      3 = v/denom+bias, relu       -> bf16 [grow][ldc]
template<int EPI, bool GATHER_A, bool BATCHED, bool CVT>
__global__ __launch_bounds__(256) void gemm_bt(
    const void* __restrict__ Abv, const void* __restrict__ Bbv,
    int M, int N, int K, int lda, int ldb, long sA, long sB,
    const int* __restrict__ gidx,
    const float* __restrict__ bias0,
    const float* __restrict__ denom, const float* __restrict__ posw,
    bf16* __restrict__ Cbf, int ldc)
{
    __shared__ __align__(16) ushort As[128 * 40];
    __shared__ __align__(16) ushort Bs[128 * 40];
    const int tid  = threadIdx.x;
    const int lane = tid & 63, wave = tid >> 6;
    const int wm = (wave >> 1) * 64, wn = (wave & 1) * 64;
    const int mt = blockIdx.x * 128, nt = blockIdx.y * 128;
    const int z  = BATCHED ? blockIdx.z : 0;

    const int srow = tid >> 1;
    const int kseg = (tid & 1) * 16;
    long arow = mt + srow;
    if (GATHER_A) {
        int g = gidx[mt + srow];
        if (g < 0 || g >= VV) g = 0;
        arow = g;
    }
    const int nrow = nt + srow;
    const bool bval = nrow < N;
    const int nrc = bval ? nrow : 0;

    const ushort* Ap16 = nullptr; const ushort* Bp16 = nullptr;
    const float*  Ap32 = nullptr; const float*  Bp32 = nullptr;
    if (CVT) {
        Ap32 = (const float*)Abv + (BATCHED ? (long)z * sA : 0l) + arow * (long)lda;
        Bp32 = (const float*)Bbv + (BATCHED ? (long)z * sB : 0l) + (long)nrc * ldb;
    } else {
        Ap16 = (const ushort*)Abv + (BATCHED ? (long)z * sA : 0l) + arow * (long)lda;
        Bp16 = (const ushort*)Bbv + (BATCHED ? (long)z * sB : 0l) + (long)nrc * ldb;
    }

    f32x4 acc[4][4];
#pragma unroll
    for (int i = 0; i < 4; ++i)
#pragma unroll
        for (int j = 0; j < 4; ++j) acc[i][j] = (f32x4){0.f, 0.f, 0.f, 0.f};

    for (int k0 = 0; k0 < K; k0 += 32) {
        __syncthreads();
#pragma unroll
        for (int hv = 0; hv < 2; ++hv) {
            const int kk = k0 + kseg + hv * 8;
            union { ushort u[8]; uint4 q; } ta, tb;
            if (CVT) {
                if (kk + 8 <= K) {
                    float4 f0 = *(const float4*)(Ap32 + kk);
                    float4 f1 = *(const float4*)(Ap32 + kk + 4);
                    ta.u[0] = f2bu(f0.x); ta.u[1] = f2bu(f0.y); ta.u[2] = f2bu(f0.z); ta.u[3] = f2bu(f0.w);
                    ta.u[4] = f2bu(f1.x); ta.u[5] = f2bu(f1.y); ta.u[6] = f2bu(f1.z); ta.u[7] = f2bu(f1.w);
                } else {
#pragma unroll
                    for (int i2 = 0; i2 < 8; ++i2) ta.u[i2] = (kk + i2 < K) ? f2bu(Ap32[kk + i2]) : (ushort)0;
                }
                if (bval && kk + 8 <= K) {
                    float4 f0 = *(const float4*)(Bp32 + kk);
                    float4 f1 = *(const float4*)(Bp32 + kk + 4);
                    tb.u[0] = f2bu(f0.x); tb.u[1] = f2bu(f0.y); tb.u[2] = f2bu(f0.z); tb.u[3] = f2bu(f0.w);
                    tb.u[4] = f2bu(f1.x); tb.u[5] = f2bu(f1.y); tb.u[6] = f2bu(f1.z); tb.u[7] = f2bu(f1.w);
                } else {
#pragma unroll
                    for (int i2 = 0; i2 < 8; ++i2) tb.u[i2] = (bval && kk + i2 < K) ? f2bu(Bp32[kk + i2]) : (ushort)0;
                }
            } else {
                if (kk + 8 <= K) {
                    u16x8v v = *(const u16x8v*)(Ap16 + kk);
#pragma unroll
                    for (int i2 = 0; i2 < 8; ++i2) ta.u[i2] = v.v[i2];
                } else {
#pragma unroll
                    for (int i2 = 0; i2 < 8; ++i2) ta.u[i2] = (kk + i2 < K) ? Ap16[kk + i2] : (ushort)0;
                }
                if (bval && kk + 8 <= K) {
                    u16x8v v = *(const u16x8v*)(Bp16 + kk);
#pragma unroll
                    for (int i2 = 0; i2 < 8; ++i2) tb.u[i2] = v.v[i2];
                } else {
#pragma unroll
                    for (int i2 = 0; i2 < 8; ++i2) tb.u[i2] = (bval && kk + i2 < K) ? Bp16[kk + i2] : (ushort)0;
                }
            }
            *(uint4*)&As[srow * 40 + kseg + hv * 8] = ta.q;
            *(uint4*)&Bs[srow * 40 + kseg + hv * 8] = tb.q;
        }
        __syncthreads();
        s16x8 af[4], bfr[4];
#pragma unroll
        for (int i = 0; i < 4; ++i)
            af[i] = *(const s16x8*)&As[(wm + i * 16 + (lane & 15)) * 40 + (lane >> 4) * 8];
#pragma unroll
        for (int j = 0; j < 4; ++j)
            bfr[j] = *(const s16x8*)&Bs[(wn + j * 16 + (lane & 15)) * 40 + (lane >> 4) * 8];
#pragma unroll
        for (int i = 0; i < 4; ++i)
#pragma unroll
            for (int j = 0; j < 4; ++j)
                acc[i][j] = __builtin_amdgcn_mfma_f32_16x16x32_bf16(af[i], bfr[j], acc[i][j], 0, 0, 0);
    }

#pragma unroll
    for (int i = 0; i < 4; ++i) {
        const int rm = mt + wm + i * 16 + ((lane >> 4) * 4);
#pragma unroll
        for (int j = 0; j < 4; ++j) {
            const int gn = nt + wn + j * 16 + (lane & 15);
            if (gn >= N) continue;
#pragma unroll
            for (int r = 0; r < 4; ++r) {
                const int gm = rm + r;
                const float v = acc[i][j][r];
                if (EPI == 0) {
                    const int bb2 = gm >> 8, tt2 = gm & 255;   // gm = b*SS + t
                    const int g3 = gn / 300, gr = gn % 300;
                    const int wgq = gr / 12, jq = gr % 12;
                    Cbf[(((long)tt2 * NWG + wgq) * BB + bb2) * 48 + g3 * 12 + jq]
                        = f2bf(v + bias0[gn]);
                } else if (EPI == 1) {
                    const int bb2 = gm >> 8, jj = gm & 255;
                    Cbf[((long)bb2 * H2 + gn) * SS + jj] = f2bf(v);
                } else {
                    const int grow = z * SS + gm;
                    float v2 = v / denom[grow] + bias0[gn];
                    v2 = fmaxf(v2, 0.f);
                    if (EPI == 2) v2 *= posw[grow];
                    Cbf[(long)grow * ldc + gn] = f2bf(v2);
                }
            }
        }
    }
}

// ---------------- LSTM recurrence: MFMA, persistent WGs, LLC-direct h, flag barrier --------
// h loads go DIRECTLY global->registers: 20 independent 8B sc1 loads per lane
// (one vmcnt wait total) -- no LDS staging, no serialized load->ds_write chain.
// k in [300,320) may read neighboring-row garbage; Bfrag is 0 there, so the
// MFMA product is unaffected (reads stay inside the workspace).
__global__ __launch_bounds__(256, 1) void k_lstm_mfma(
    const bf16* __restrict__ gatesF, const bf16* __restrict__ gatesB,
    const float* __restrict__ WhhF, const float* __restrict__ WhhB,
    bf16* __restrict__ hgbase,   // [2dirs][2bufs][64][HPITCH] zeroed
    int* __restrict__ flagbase,  // [2][256][32] zeroed
    float* __restrict__ text_out, int dir_base)
{
    const int dir = dir_base + blockIdx.x / NWG;
    const int wg  = blockIdx.x % NWG;
    const ushort* gu  = (const ushort*)(dir ? gatesB : gatesF);
    const float*  Whh = dir ? WhhB : WhhF;
    ushort* hg   = (ushort*)hgbase + (long)dir * (2 * 64 * HPITCH);
    int*   flags = flagbase + dir * (256 * 32);

    const int tid = threadIdx.x, lane = tid & 63, wave = tid >> 6;
    __shared__ float cbuf[64 * CPW];

    const int nl15 = lane & 15;
    const int kq = lane >> 4;
    const int gI = nl15 & 3;   // gate index: 0=i 1=f 2=g 3=o
    // ---- W_hh slice -> register B-fragments (once) ----
    s16x8 Bfrag[3][10];
#pragma unroll
    for (int tt = 0; tt < 3; ++tt) {
        const int j = (tt * 16 + nl15) >> 2;   // 0..11
        const float* wrow = Whh + ((long)(gI * HH + wg * CPW + j)) * HH;
        const int kb = kq * 8;
        for (int ss = 0; ss < 10; ++ss) {
            union { ushort u[8]; s16x8 v; } tb;
#pragma unroll
            for (int e = 0; e < 8; ++e) {
                const int k = ss * 32 + kb + e;
                tb.u[e] = (k < HH) ? f2bu(wrow[k]) : (ushort)0;
            }
            Bfrag[tt][ss] = tb.v;
        }
    }
    for (int i = tid; i < 64 * CPW; i += 256) cbuf[i] = 0.f;
    __syncthreads();

    // A-fragment source row for this lane: m = wave*16 + nl15
    const int am = wave * 16 + nl15;

    // ---- gate-value register prefetch (step 0); WG-blocked layout ----
    ushort gcur[3][4], gnxt[3][4];
    {
        const int tcur = dir ? (SS - 1) : 0;
#pragma unroll
        for (int tt = 0; tt < 3; ++tt) {
            const int col48 = gI * 12 + ((tt * 16 + nl15) >> 2);
#pragma unroll
            for (int r = 0; r < 4; ++r) {
                const int mb = wave * 16 + (kq << 2) + r;
                gcur[tt][r] = gu[(((long)tcur * NWG + wg) * BB + mb) * 48 + col48];
            }
        }
    }

    for (int s = 0; s < SS; ++s) {
        const int t = dir ? (SS - 1 - s) : s;
        const int rb = s & 1;
        // ---- direct global->register A-fragment loads (20 parallel 8B sc1) ----
        unsigned long long hq[20];
        {
            const unsigned long long* src =
                (const unsigned long long*)(hg + rb * (64 * HPITCH)) + (long)am * 76;
#pragma unroll
            for (int ss = 0; ss < 10; ++ss) {
                hq[2 * ss]     = __hip_atomic_load(&src[ss * 8 + kq * 2],
                                                   __ATOMIC_RELAXED, __HIP_MEMORY_SCOPE_AGENT);
                hq[2 * ss + 1] = __hip_atomic_load(&src[ss * 8 + kq * 2 + 1],
                                                   __ATOMIC_RELAXED, __HIP_MEMORY_SCOPE_AGENT);
            }
        }
        // ---- MFMA: C[16 x 48] per wave, A straight from registers ----
        f32x4 acc[3];
#pragma unroll
        for (int tt = 0; tt < 3; ++tt) acc[tt] = (f32x4){0.f, 0.f, 0.f, 0.f};
#pragma unroll
        for (int ss = 0; ss < 10; ++ss) {
            union { unsigned long long q[2]; s16x8 v; } ua;
            ua.q[0] = hq[2 * ss]; ua.q[1] = hq[2 * ss + 1];
#pragma unroll
            for (int tt = 0; tt < 3; ++tt)
                acc[tt] = __builtin_amdgcn_mfma_f32_16x16x32_bf16(ua.v, Bfrag[tt][ss], acc[tt], 0, 0, 0);
        }
        // ---- epilogue: activations, c,h update; h via sc1, text_out plain ----
        ushort* hw = hg + (rb ^ 1) * (64 * HPITCH);
#pragma unroll
        for (int tt = 0; tt < 3; ++tt) {
            const int j = (tt * 16 + nl15) >> 2;
            const int hc = wg * CPW + j;
#pragma unroll
            for (int r = 0; r < 4; ++r) {
                const int mb = wave * 16 + (kq << 2) + r;
                const bf16 gb = *(const bf16*)&gcur[tt][r];
                const float val = acc[tt][r] + bf2f(gb);
                const float a = (gI == 2) ? ftanh(val) : fsig(val);
                const float v1 = __shfl_xor(a, 1);
                const float v2 = __shfl_xor(a, 2);
                const float v3 = __shfl_xor(a, 3);
                if (gI == 0) {
                    const int ci = mb * CPW + j;
                    const float c = v1 * cbuf[ci] + a * v2;
                    cbuf[ci] = c;
                    const float h = v3 * ftanh(c);
                    bf16 hb = f2bf(h);
                    __hip_atomic_store(&hw[mb * HPITCH + hc], *(ushort*)&hb,
                                       __ATOMIC_RELAXED, __HIP_MEMORY_SCOPE_AGENT);
                    text_out[((long)(mb * SS + t)) * H2 + dir * HH + hc] = h;
                }
            }
        }
        if (s == SS - 1) break;
        __syncthreads();   // s_waitcnt vmcnt(0) + s_barrier => h stores acked at LLC
        if (tid == 0)
            __hip_atomic_store(&flags[s * 32 + wg], 1, __ATOMIC_RELAXED, __HIP_MEMORY_SCOPE_AGENT);
        // prefetch next step's gates while waiting (contiguous 6KB/WG block)
        {
            const int tn = dir ? (SS - 2 - s) : (s + 1);
#pragma unroll
            for (int tt = 0; tt < 3; ++tt) {
                const int col48 = gI * 12 + ((tt * 16 + nl15) >> 2);
#pragma unroll
                for (int r = 0; r < 4; ++r) {
                    const int mb = wave * 16 + (kq << 2) + r;
                    gnxt[tt][r] = gu[(((long)tn * NWG + wg) * BB + mb) * 48 + col48];
                }
            }
        }
        if (tid < NWG) {
            while (__hip_atomic_load(&flags[s * 32 + tid], __ATOMIC_RELAXED,
                                     __HIP_MEMORY_SCOPE_AGENT) == 0) { }
        }
        __syncthreads();
#pragma unroll
        for (int tt = 0; tt < 3; ++tt)
#pragma unroll
            for (int r = 0; r < 4; ++r) gcur[tt][r] = gnxt[tt][r];
    }
}

// ---------------- relation scores -> adj scatter ----------------
__global__ void k_scores(const float* __restrict__ text_out, const float* __restrict__ P,
                         const int* __restrict__ head, const int* __restrict__ behead,
                         const int* __restrict__ rel, const float* __restrict__ bil_b,
                         bf16* __restrict__ adj, float* __restrict__ denom)
{
    const int gw = (blockIdx.x * blockDim.x + threadIdx.x) >> 6;
    const int lane = threadIdx.x & 63;
    if (gw >= BB * RR) return;
    const int b = gw >> 9, r = gw & 511;
    int rl = rel[b * RR + r];     if (rl < 0 || rl > 45) rl = 0;
    int hd = head[b * RR + r]   & 255;
    int bh = behead[b * RR + r] & 255;
    const float* n1 = text_out + ((long)(b * SS + hd)) * H2;
    const float* n2 = text_out + ((long)(b * SS + bh)) * H2;
    float part = 0.f;
    for (int i = lane; i < H2; i += 64) {
        part += n1[i] * P[(long)i * 46 + rl];
        part += n2[i] * P[(long)(H2 + i) * 46 + rl];
    }
    for (int off = 32; off; off >>= 1) part += __shfl_down(part, off);
    if (lane == 0) {
        const float sc = 1.f / (1.f + expf(-(part + bil_b[0])));
        adj[((long)(b * SS + hd)) * SS + bh] = f2bf(sc);
        atomicAdd(&denom[b * SS + hd], sc);
    }
}

// ---------------- pooled attention + FC ----------------
__global__ __launch_bounds__(256) void k_attn(
    const float* __restrict__ text_out, const bf16* __restrict__ x2,
    const int* __restrict__ l0l1, const float* __restrict__ fcW,
    const float* __restrict__ fcb, float* __restrict__ out)
{
    const int b = blockIdx.x, tid = threadIdx.x;
    const int wave = tid >> 6, lane = tid & 63;
    __shared__ float xs[H2];
    __shared__ float sc[SS];
    __shared__ float red[16];
    const int l0 = l0l1[b * 2], l1 = l0l1[b * 2 + 1];
    for (int n = tid; n < H2; n += 256) {
        float s = 0.f;
        for (int i = l0; i <= l1 && i < SS; ++i) s += bf2f(x2[((long)(b * SS + i)) * H2 + n]);
        xs[n] = s;
    }
    __syncthreads();
    for (int j = wave; j < SS; j += 4) {
        const float* row = text_out + ((long)(b * SS + j)) * H2;
        float p = 0.f;
        for (int n = lane; n < H2; n += 64) p += xs[n] * row[n];
        for (int off = 32; off; off >>= 1) p += __shfl_down(p, off);
        if (lane == 0) sc[j] = p;
    }
    __syncthreads();
    const float v = sc[tid];
    float mx = v;
    for (int off = 32; off; off >>= 1) mx = fmaxf(mx, __shfl_down(mx, off));
    if (lane == 0) red[wave] = mx;
    __syncthreads();
    if (tid == 0) red[8] = fmaxf(fmaxf(red[0], red[1]), fmaxf(red[2], red[3]));
    __syncthreads();
    const float e = expf(v - red[8]);
    sc[tid] = e;
    float sm = e;
    for (int off = 32; off; off >>= 1) sm += __shfl_down(sm, off);
    if (lane == 0) red[wave] = sm;
    __syncthreads();
    if (tid == 0) red[9] = red[0] + red[1] + red[2] + red[3];
    __syncthreads();
    const float inv = 1.f / red[9];
    for (int n = tid; n < H2; n += 256) {
        float a = 0.f;
        for (int j = 0; j < SS; ++j) a += sc[j] * text_out[((long)(b * SS + j)) * H2 + n];
        xs[n] = a * inv;
    }
    __syncthreads();
    if (wave < 3) {
        float p = 0.f;
        for (int n = lane; n < H2; n += 64) p += xs[n] * fcW[n * 3 + wave];
        for (int off = 32; off; off >>= 1) p += __shfl_down(p, off);
        if (lane == 0) out[b * 3 + wave] = p + fcb[wave];
    }
}

extern "C" void kernel_launch(void* const* d_in, const int* in_sizes, int n_in,
                              void* d_out, int out_size, void* d_ws, size_t ws_size,
                              hipStream_t stream) {
    const int*   text_idx   = (const int*)d_in[0];
    const int*   aspect_idx = (const int*)d_in[1];
    const int*   left_idx   = (const int*)d_in[2];
    const int*   head       = (const int*)d_in[4];
    const int*   behead     = (const int*)d_in[5];
    const int*   rel        = (const int*)d_in[6];
    const float* embed      = (const float*)d_in[7];
    const float* relE       = (const float*)d_in[8];
    const float* Wf_ih      = (const float*)d_in[9];
    const float* Wf_hh      = (const float*)d_in[10];
    const float* bf_b       = (const float*)d_in[11];
    const float* Wb_ih      = (const float*)d_in[12];
    const float* Wb_hh      = (const float*)d_in[13];
    const float* bb_b       = (const float*)d_in[14];
    const float* bilW       = (const float*)d_in[15];
    const float* bilb       = (const float*)d_in[16];
    const float* gc1W       = (const float*)d_in[17];
    const float* gc1b       = (const float*)d_in[18];
    const float* gc2W       = (const float*)d_in[19];
    const float* gc2b       = (const float*)d_in[20];
    const float* fcW        = (const float*)d_in[21];
    const float* fcb        = (const float*)d_in[22];

    const bool  conc  = ws_size >= CONC_END;
    const size_t base2 = conc ? GATES_SZ : 0ul;

    char* ws = (char*)d_ws;
    bf16*  gatesF   = (bf16*)(ws);
    bf16*  gatesB   = conc ? (bf16*)(ws + GATES_SZ) : gatesF;
    bf16*  slot0bf  = (bf16*)(ws);                 // pw1/pw2/x2 (gates dead after LSTM)
    bf16*  slot1bf  = (bf16*)(ws + SLOTSZ);        // h1T/h2T
    float* text_out = (float*)(ws + OFF_TEXT  + base2);
    bf16*  adjw     = (bf16*)(ws + OFF_ADJ    + base2);
    float* P        = (float*)(ws + OFF_P     + base2);
    float* denom    = (float*)(ws + OFF_DENOM + base2);
    float* posw     = (float*)(ws + OFF_POSW  + base2);
    int*   l0l1     = (int*)(ws + OFF_L0L1    + base2);
    bf16*  W1T      = (bf16*)(ws + OFF_W1T    + base2);
    bf16*  W2T      = (bf16*)(ws + OFF_W2T    + base2);
    bf16*  hgbase   = (bf16*)(ws + OFF_HG     + base2);
    int*   flagbase = (int*)(ws + OFF_FLAGS   + base2);

    dim3 blk(256);

    hipMemsetAsync(adjw, 0, (size_t)BB * SS * SS * 2, stream);
    hipMemsetAsync(hgbase, 0, 155648 + 65536, stream);   // h buffers + flags
    k_init_denom<<<64, blk, 0, stream>>>(denom);
    k_lengths<<<64, blk, 0, stream>>>(text_idx, aspect_idx, left_idx, l0l1, posw);
    k_P<<<(G4 * 46 + 255) / 256, blk, 0, stream>>>(bilW, relE, P);
    k_transpose600<<<(H2 * H2 + 255) / 256, blk, 0, stream>>>(gc1W, W1T);
    k_transpose600<<<(H2 * H2 + 255) / 256, blk, 0, stream>>>(gc2W, W2T);

    if (conc) {
        gemm_bt<0, true, false, true><<<dim3(128, 10), blk, 0, stream>>>(
            embed, Wf_ih, 16384, G4, EE, EE, EE, 0, 0,
            text_idx, bf_b, nullptr, nullptr, gatesF, G4);
        gemm_bt<0, true, false, true><<<dim3(128, 10), blk, 0, stream>>>(
            embed, Wb_ih, 16384, G4, EE, EE, EE, 0, 0,
            text_idx, bb_b, nullptr, nullptr, gatesB, G4);
        k_lstm_mfma<<<2 * NWG, blk, 0, stream>>>(
            gatesF, gatesB, Wf_hh, Wb_hh, hgbase, flagbase, text_out, 0);
    } else {
        gemm_bt<0, true, false, true><<<dim3(128, 10), blk, 0, stream>>>(
            embed, Wf_ih, 16384, G4, EE, EE, EE, 0, 0,
            text_idx, bf_b, nullptr, nullptr, gatesF, G4);
        k_lstm_mfma<<<NWG, blk, 0, stream>>>(
            gatesF, gatesB, Wf_hh, Wb_hh, hgbase, flagbase, text_out, 0);
        gemm_bt<0, true, false, true><<<dim3(128, 10), blk, 0, stream>>>(
            embed, Wb_ih, 16384, G4, EE, EE, EE, 0, 0,
            text_idx, bb_b, nullptr, nullptr, gatesB, G4);
        k_lstm_mfma<<<NWG, blk, 0, stream>>>(
            gatesF, gatesB, Wf_hh, Wb_hh, hgbase, flagbase, text_out, 1);
    }

    k_scores<<<(BB * RR * 64 + 255) / 256, blk, 0, stream>>>(
        text_out, P, head, behead, rel, bilb, adjw, denom);
    k_pw1<<<(16384 * H2 + 255) / 256, blk, 0, stream>>>(text_out, posw, slot0bf);

    gemm_bt<1, false, false, false><<<dim3(128, 5), blk, 0, stream>>>(
        slot0bf, W1T, 16384, H2, H2, H2, H2, 0, 0,
        nullptr, nullptr, nullptr, nullptr, slot1bf, 0);
    gemm_bt<2, false, true, false><<<dim3(2, 5, 64), blk, 0, stream>>>(
        adjw, slot1bf, SS, H2, SS, SS, SS, (long)SS * SS, (long)H2 * SS,
        nullptr, gc1b, denom, posw, slot0bf, H2);
    gemm_bt<1, false, false, false><<<dim3(128, 5), blk, 0, stream>>>(
        slot0bf, W2T, 16384, H2, H2, H2, H2, 0, 0,
        nullptr, nullptr, nullptr, nullptr, slot1bf, 0);
    gemm_bt<3, false, true, false><<<dim3(2, 5, 64), blk, 0, stream>>>(
        adjw, slot1bf, SS, H2, SS, SS, SS, (long)SS * SS, (long)H2 * SS,
        nullptr, gc2b, denom, posw, slot0bf, H2);

    k_attn<<<64, blk, 0, stream>>>(text_out, slot0bf, l0l1, fcW, fcb, (float*)d_out);
}

// Round 10
// 2031.655 us; speedup vs baseline: 1.7442x; 1.0271x over previous
//
#include <hip/hip_runtime.h>
#include <hip/hip_bf16.h>

typedef __hip_bfloat16 bf16;
using f32x4 = __attribute__((ext_vector_type(4))) float;
using s16x8 = __attribute__((ext_vector_type(8))) short;

#define DEV __device__ __forceinline__
DEV float bf2f(bf16 x) { return __bfloat162float(x); }
DEV bf16  f2bf(float x) { return __float2bfloat16(x); }
DEV ushort f2bu(float x) { bf16 h = __float2bfloat16(x); return *(ushort*)&h; }
DEV float fsig(float x)  { return 1.f / (1.f + __expf(-x)); }
DEV float ftanh(float x) {
    float xc = fminf(fmaxf(x, -15.f), 15.f);
    float e = __expf(2.f * xc);
    return (e - 1.f) / (e + 1.f);
}

#define BB 64
#define SS 256
#define EE 300
#define HH 300
#define H2 600
#define G4 1200
#define RR 512
#define VV 30000

#define NWG 25
#define CPW 12      // h-columns per WG  (25*12 = 300)
#define HPITCH 304  // published-h row pitch (ushorts) = 76 qwords

#define SLOTSZ   19660800ul
#define GATES_SZ 39321600ul
#define OFF_TEXT  39321600ul   // f32 [16384][600]
#define OFF_ADJ   78643200ul   // bf16 [64][256][256]
#define OFF_P     87031808ul   // f32 [1200][46]
#define OFF_DENOM 87252608ul
#define OFF_POSW  87318144ul
#define OFF_L0L1  87383680ul
#define OFF_W1T   87384704ul
#define OFF_W2T   88104704ul
#define OFF_HG    88824704ul   // bf16 [2dirs][2bufs][64][304] = 155648 B
#define OFF_FLAGS 88980352ul   // int  [2][256][32] = 65536 B
#define SEQ_END   89045888ul
#define CONC_END  128367488ul

struct __attribute__((packed, aligned(4))) u16x8v { ushort v[8]; };

// ---------------- small prep kernels ----------------
__global__ void k_lengths(const int* __restrict__ text_idx,
                          const int* __restrict__ aspect_idx,
                          const int* __restrict__ left_idx,
                          int* __restrict__ l0l1, float* __restrict__ posw,
                          float* __restrict__ denom) {
    int b = blockIdx.x, tid = threadIdx.x;
    __shared__ int cnt[3];
    if (tid < 3) cnt[tid] = 0;
    __syncthreads();
    if (text_idx[b * SS + tid] != 0) atomicAdd(&cnt[0], 1);
    if (tid < 4 && aspect_idx[b * 4 + tid] != 0) atomicAdd(&cnt[1], 1);
    if (tid < 64 && left_idx[b * 64 + tid] != 0) atomicAdd(&cnt[2], 1);
    __syncthreads();
    int tl = cnt[0], al = cnt[1], ll = cnt[2];
    int l0 = ll, l1 = ll + al - 1;
    if (tid == 0) { l0l1[b * 2] = l0; l0l1[b * 2 + 1] = l1; }
    float ctx = fmaxf((float)(tl - al), 1.f);
    float j = (float)tid, l0f = (float)l0, l1f = (float)l1, tlf = (float)tl;
    float w;
    if (j < l0f)       w = 1.f - (l0f - j) / ctx;
    else if (j <= l1f) w = 0.f;
    else if (j < tlf)  w = 1.f - (j - l1f) / ctx;
    else               w = 0.f;
    posw[b * SS + tid] = w;
    denom[b * SS + tid] = 1.f;
}

__global__ void k_P(const float* __restrict__ bilW, const float* __restrict__ relE,
                    float* __restrict__ P) {
    int id = blockIdx.x * 256 + threadIdx.x;
    if (id >= G4 * 46) return;
    int i = id / 46, r = id % 46;
    float s = 0.f;
    for (int j = 0; j < 50; ++j) s += bilW[i * 50 + j] * relE[r * 50 + j];
    P[id] = s;
}

__global__ void k_transpose2(const float* __restrict__ Wa, const float* __restrict__ Wb,
                             bf16* __restrict__ Ta, bf16* __restrict__ Tb) {
    int id = blockIdx.x * 256 + threadIdx.x;
    if (id >= 2 * H2 * H2) return;
    const float* W = (id < H2 * H2) ? Wa : Wb;
    bf16* T = (id < H2 * H2) ? Ta : Tb;
    int l = (id < H2 * H2) ? id : id - H2 * H2;
    int n = l / H2, k = l % H2;
    T[l] = f2bf(W[k * H2 + n]);
}

// ---------------- MFMA GEMM: C = A * B^T ----------------
// EPI: 0 = +bias, store bf16 WG-blocked gates: [(t*25+wg)*64+b][48]; gn>=1200 -> Cbf2/bias1
//      1 = store bf16 transposed per batch [b][n][j], m=b*256+j
//      2 = v/denom+bias, relu, *posw -> bf16 [grow][ldc]
//      3 = v/denom+bias, relu       -> bf16 [grow][ldc]
// CVTA/CVTB: A/B are f32, converted while staging. ASCALE: A row scaled by ascale[arow].
template<int EPI, bool GATHER_A, bool BATCHED, bool CVTA, bool CVTB, bool ASCALE>
__global__ __launch_bounds__(256) void gemm_bt(
    const void* __restrict__ Abv, const void* __restrict__ Bbv, const void* __restrict__ B2v,
    int M, int N, int K, int lda, int ldb, long sA, long sB,
    const int* __restrict__ gidx,
    const float* __restrict__ bias0, const float* __restrict__ bias1,
    const float* __restrict__ ascale,
    const float* __restrict__ denom, const float* __restrict__ posw,
    bf16* __restrict__ Cbf, bf16* __restrict__ Cbf2, int ldc)
{
    __shared__ __align__(16) ushort As[128 * 40];
    __shared__ __align__(16) ushort Bs[128 * 40];
    const int tid  = threadIdx.x;
    const int lane = tid & 63, wave = tid >> 6;
    const int wm = (wave >> 1) * 64, wn = (wave & 1) * 64;
    const int mt = blockIdx.x * 128, nt = blockIdx.y * 128;
    const int z  = BATCHED ? blockIdx.z : 0;

    const int srow = tid >> 1;
    const int kseg = (tid & 1) * 16;
    long arow = mt + srow;
    if (GATHER_A) {
        int g = gidx[mt + srow];
        if (g < 0 || g >= VV) g = 0;
        arow = g;
    }
    const int nrow = nt + srow;
    const bool bval = nrow < N;
    const int nrc = bval ? nrow : 0;

    const ushort* Ap16 = nullptr; const ushort* Bp16 = nullptr;
    const float*  Ap32 = nullptr; const float*  Bp32 = nullptr;
    if (CVTA) {
        Ap32 = (const float*)Abv + (BATCHED ? (long)z * sA : 0l) + arow * (long)lda;
    } else {
        Ap16 = (const ushort*)Abv + (BATCHED ? (long)z * sA : 0l) + arow * (long)lda;
    }
    if (CVTB) {
        if (EPI == 0) {
            Bp32 = (nrc < G4) ? (const float*)Bbv + (long)nrc * ldb
                              : (const float*)B2v + (long)(nrc - G4) * ldb;
        } else {
            Bp32 = (const float*)Bbv + (BATCHED ? (long)z * sB : 0l) + (long)nrc * ldb;
        }
    } else {
        Bp16 = (const ushort*)Bbv + (BATCHED ? (long)z * sB : 0l) + (long)nrc * ldb;
    }
    const float asc = ASCALE ? ascale[arow] : 1.f;

    f32x4 acc[4][4];
#pragma unroll
    for (int i = 0; i < 4; ++i)
#pragma unroll
        for (int j = 0; j < 4; ++j) acc[i][j] = (f32x4){0.f, 0.f, 0.f, 0.f};

    for (int k0 = 0; k0 < K; k0 += 32) {
        __syncthreads();
#pragma unroll
        for (int hv = 0; hv < 2; ++hv) {
            const int kk = k0 + kseg + hv * 8;
            union { ushort u[8]; uint4 q; } ta, tb;
            if (CVTA) {
                if (kk + 8 <= K) {
                    float4 f0 = *(const float4*)(Ap32 + kk);
                    float4 f1 = *(const float4*)(Ap32 + kk + 4);
                    ta.u[0] = f2bu(asc * f0.x); ta.u[1] = f2bu(asc * f0.y);
                    ta.u[2] = f2bu(asc * f0.z); ta.u[3] = f2bu(asc * f0.w);
                    ta.u[4] = f2bu(asc * f1.x); ta.u[5] = f2bu(asc * f1.y);
                    ta.u[6] = f2bu(asc * f1.z); ta.u[7] = f2bu(asc * f1.w);
                } else {
#pragma unroll
                    for (int i2 = 0; i2 < 8; ++i2)
                        ta.u[i2] = (kk + i2 < K) ? f2bu(asc * Ap32[kk + i2]) : (ushort)0;
                }
            } else {
                if (kk + 8 <= K) {
                    u16x8v v = *(const u16x8v*)(Ap16 + kk);
#pragma unroll
                    for (int i2 = 0; i2 < 8; ++i2) ta.u[i2] = v.v[i2];
                } else {
#pragma unroll
                    for (int i2 = 0; i2 < 8; ++i2) ta.u[i2] = (kk + i2 < K) ? Ap16[kk + i2] : (ushort)0;
                }
            }
            if (CVTB) {
                if (bval && kk + 8 <= K) {
                    float4 f0 = *(const float4*)(Bp32 + kk);
                    float4 f1 = *(const float4*)(Bp32 + kk + 4);
                    tb.u[0] = f2bu(f0.x); tb.u[1] = f2bu(f0.y); tb.u[2] = f2bu(f0.z); tb.u[3] = f2bu(f0.w);
                    tb.u[4] = f2bu(f1.x); tb.u[5] = f2bu(f1.y); tb.u[6] = f2bu(f1.z); tb.u[7] = f2bu(f1.w);
                } else {
#pragma unroll
                    for (int i2 = 0; i2 < 8; ++i2)
                        tb.u[i2] = (bval && kk + i2 < K) ? f2bu(Bp32[kk + i2]) : (ushort)0;
                }
            } else {
                if (bval && kk + 8 <= K) {
                    u16x8v v = *(const u16x8v*)(Bp16 + kk);
#pragma unroll
                    for (int i2 = 0; i2 < 8; ++i2) tb.u[i2] = v.v[i2];
                } else {
#pragma unroll
                    for (int i2 = 0; i2 < 8; ++i2) tb.u[i2] = (bval && kk + i2 < K) ? Bp16[kk + i2] : (ushort)0;
                }
            }
            *(uint4*)&As[srow * 40 + kseg + hv * 8] = ta.q;
            *(uint4*)&Bs[srow * 40 + kseg + hv * 8] = tb.q;
        }
        __syncthreads();
        s16x8 af[4], bfr[4];
#pragma unroll
        for (int i = 0; i < 4; ++i)
            af[i] = *(const s16x8*)&As[(wm + i * 16 + (lane & 15)) * 40 + (lane >> 4) * 8];
#pragma unroll
        for (int j = 0; j < 4; ++j)
            bfr[j] = *(const s16x8*)&Bs[(wn + j * 16 + (lane & 15)) * 40 + (lane >> 4) * 8];
#pragma unroll
        for (int i = 0; i < 4; ++i)
#pragma unroll
            for (int j = 0; j < 4; ++j)
                acc[i][j] = __builtin_amdgcn_mfma_f32_16x16x32_bf16(af[i], bfr[j], acc[i][j], 0, 0, 0);
    }

#pragma unroll
    for (int i = 0; i < 4; ++i) {
        const int rm = mt + wm + i * 16 + ((lane >> 4) * 4);
#pragma unroll
        for (int j = 0; j < 4; ++j) {
            const int gn = nt + wn + j * 16 + (lane & 15);
            if (gn >= N) continue;
#pragma unroll
            for (int r = 0; r < 4; ++r) {
                const int gm = rm + r;
                const float v = acc[i][j][r];
                if (EPI == 0) {
                    const int bb2 = gm >> 8, tt2 = gm & 255;   // gm = b*SS + t
                    bf16* dst = Cbf; int gl = gn; float bia;
                    if (gn < G4) { bia = bias0[gn]; }
                    else { dst = Cbf2; gl = gn - G4; bia = bias1[gl]; }
                    const int g3 = gl / 300, gr = gl % 300;
                    const int wgq = gr / 12, jq = gr % 12;
                    dst[(((long)tt2 * NWG + wgq) * BB + bb2) * 48 + g3 * 12 + jq]
                        = f2bf(v + bia);
                } else if (EPI == 1) {
                    const int bb2 = gm >> 8, jj = gm & 255;
                    Cbf[((long)bb2 * H2 + gn) * SS + jj] = f2bf(v);
                } else {
                    const int grow = z * SS + gm;
                    float v2 = v / denom[grow] + bias0[gn];
                    v2 = fmaxf(v2, 0.f);
                    if (EPI == 2) v2 *= posw[grow];
                    Cbf[(long)grow * ldc + gn] = f2bf(v2);
                }
            }
        }
    }
}

// ---------------- LSTM recurrence: MFMA, persistent WGs, LLC-direct h, flag barrier --------
// h loads DIRECT global->registers (20 parallel 8B sc1 loads, one vmcnt wait).
// c-state in registers (same lane owns same (mb,j) every step). text_out
// stores issued AFTER the flag store (off the pre-flag vmcnt drain).
__global__ __launch_bounds__(256, 1) void k_lstm_mfma(
    const bf16* __restrict__ gatesF, const bf16* __restrict__ gatesB,
    const float* __restrict__ WhhF, const float* __restrict__ WhhB,
    bf16* __restrict__ hgbase,   // [2dirs][2bufs][64][HPITCH] zeroed
    int* __restrict__ flagbase,  // [2][256][32] zeroed
    float* __restrict__ text_out, int dir_base)
{
    const int dir = dir_base + blockIdx.x / NWG;
    const int wg  = blockIdx.x % NWG;
    const ushort* gu  = (const ushort*)(dir ? gatesB : gatesF);
    const float*  Whh = dir ? WhhB : WhhF;
    ushort* hg   = (ushort*)hgbase + (long)dir * (2 * 64 * HPITCH);
    int*   flags = flagbase + dir * (256 * 32);

    const int tid = threadIdx.x, lane = tid & 63, wave = tid >> 6;
    const int nl15 = lane & 15;
    const int kq = lane >> 4;
    const int gI = nl15 & 3;   // gate index: 0=i 1=f 2=g 3=o

    // ---- W_hh slice -> register B-fragments (once) ----
    s16x8 Bfrag[3][10];
#pragma unroll
    for (int tt = 0; tt < 3; ++tt) {
        const int j = (tt * 16 + nl15) >> 2;   // 0..11
        const float* wrow = Whh + ((long)(gI * HH + wg * CPW + j)) * HH;
        const int kb = kq * 8;
        for (int ss = 0; ss < 10; ++ss) {
            union { ushort u[8]; s16x8 v; } tb;
#pragma unroll
            for (int e = 0; e < 8; ++e) {
                const int k = ss * 32 + kb + e;
                tb.u[e] = (k < HH) ? f2bu(wrow[k]) : (ushort)0;
            }
            Bfrag[tt][ss] = tb.v;
        }
    }
    float cval[3][4];
#pragma unroll
    for (int tt = 0; tt < 3; ++tt)
#pragma unroll
        for (int r = 0; r < 4; ++r) cval[tt][r] = 0.f;

    const int am = wave * 16 + nl15;   // A-fragment source row

    // ---- gate-value register prefetch (step 0) ----
    ushort gcur[3][4], gnxt[3][4];
    {
        const int tcur = dir ? (SS - 1) : 0;
#pragma unroll
        for (int tt = 0; tt < 3; ++tt) {
            const int col48 = gI * 12 + ((tt * 16 + nl15) >> 2);
#pragma unroll
            for (int r = 0; r < 4; ++r) {
                const int mb = wave * 16 + (kq << 2) + r;
                gcur[tt][r] = gu[(((long)tcur * NWG + wg) * BB + mb) * 48 + col48];
            }
        }
    }

    for (int s = 0; s < SS; ++s) {
        const int t = dir ? (SS - 1 - s) : s;
        const int rb = s & 1;
        // ---- direct global->register A-fragment loads (20 parallel 8B sc1) ----
        unsigned long long hq[20];
        {
            const unsigned long long* src =
                (const unsigned long long*)(hg + rb * (64 * HPITCH)) + (long)am * 76;
#pragma unroll
            for (int ss = 0; ss < 10; ++ss) {
                hq[2 * ss]     = __hip_atomic_load(&src[ss * 8 + kq * 2],
                                                   __ATOMIC_RELAXED, __HIP_MEMORY_SCOPE_AGENT);
                hq[2 * ss + 1] = __hip_atomic_load(&src[ss * 8 + kq * 2 + 1],
                                                   __ATOMIC_RELAXED, __HIP_MEMORY_SCOPE_AGENT);
            }
        }
        // ---- MFMA: C[16 x 48] per wave, A straight from registers ----
        f32x4 acc[3];
#pragma unroll
        for (int tt = 0; tt < 3; ++tt) acc[tt] = (f32x4){0.f, 0.f, 0.f, 0.f};
#pragma unroll
        for (int ss = 0; ss < 10; ++ss) {
            union { unsigned long long q[2]; s16x8 v; } ua;
            ua.q[0] = hq[2 * ss]; ua.q[1] = hq[2 * ss + 1];
#pragma unroll
            for (int tt = 0; tt < 3; ++tt)
                acc[tt] = __builtin_amdgcn_mfma_f32_16x16x32_bf16(ua.v, Bfrag[tt][ss], acc[tt], 0, 0, 0);
        }
        // ---- epilogue: activations, c,h update; h via sc1 ----
        ushort* hw = hg + (rb ^ 1) * (64 * HPITCH);
        float hval[3][4];
#pragma unroll
        for (int tt = 0; tt < 3; ++tt) {
            const int j = (tt * 16 + nl15) >> 2;
            const int hc = wg * CPW + j;
#pragma unroll
            for (int r = 0; r < 4; ++r) {
                const int mb = wave * 16 + (kq << 2) + r;
                const bf16 gb = *(const bf16*)&gcur[tt][r];
                const float val = acc[tt][r] + bf2f(gb);
                const float a = (gI == 2) ? ftanh(val) : fsig(val);
                const float v1 = __shfl_xor(a, 1);
                const float v2 = __shfl_xor(a, 2);
                const float v3 = __shfl_xor(a, 3);
                if (gI == 0) {
                    const float c = v1 * cval[tt][r] + a * v2;
                    cval[tt][r] = c;
                    const float h = v3 * ftanh(c);
                    hval[tt][r] = h;
                    bf16 hb = f2bf(h);
                    __hip_atomic_store(&hw[mb * HPITCH + hc], *(ushort*)&hb,
                                       __ATOMIC_RELAXED, __HIP_MEMORY_SCOPE_AGENT);
                }
            }
        }
        if (s < SS - 1) {
            __syncthreads();   // vmcnt(0): h sc1 stores acked at LLC
            if (tid == 0)
                __hip_atomic_store(&flags[s * 32 + wg], 1, __ATOMIC_RELAXED, __HIP_MEMORY_SCOPE_AGENT);
        }
        // text_out stores off the critical drain (overlap spin window)
#pragma unroll
        for (int tt = 0; tt < 3; ++tt) {
            const int hc = wg * CPW + ((tt * 16 + nl15) >> 2);
#pragma unroll
            for (int r = 0; r < 4; ++r) {
                const int mb = wave * 16 + (kq << 2) + r;
                if (gI == 0)
                    text_out[((long)(mb * SS + t)) * H2 + dir * HH + hc] = hval[tt][r];
            }
        }
        if (s == SS - 1) break;
        // prefetch next step's gates while waiting (contiguous 6KB/WG block)
        {
            const int tn = dir ? (SS - 2 - s) : (s + 1);
#pragma unroll
            for (int tt = 0; tt < 3; ++tt) {
                const int col48 = gI * 12 + ((tt * 16 + nl15) >> 2);
#pragma unroll
                for (int r = 0; r < 4; ++r) {
                    const int mb = wave * 16 + (kq << 2) + r;
                    gnxt[tt][r] = gu[(((long)tn * NWG + wg) * BB + mb) * 48 + col48];
                }
            }
        }
        if (tid < NWG) {
            while (__hip_atomic_load(&flags[s * 32 + tid], __ATOMIC_RELAXED,
                                     __HIP_MEMORY_SCOPE_AGENT) == 0) { }
        }
        __syncthreads();
#pragma unroll
        for (int tt = 0; tt < 3; ++tt)
#pragma unroll
            for (int r = 0; r < 4; ++r) gcur[tt][r] = gnxt[tt][r];
    }
}

// ---------------- relation scores -> adj scatter ----------------
__global__ void k_scores(const float* __restrict__ text_out, const float* __restrict__ P,
                         const int* __restrict__ head, const int* __restrict__ behead,
                         const int* __restrict__ rel, const float* __restrict__ bil_b,
                         bf16* __restrict__ adj, float* __restrict__ denom)
{
    const int gw = (blockIdx.x * blockDim.x + threadIdx.x) >> 6;
    const int lane = threadIdx.x & 63;
    if (gw >= BB * RR) return;
    const int b = gw >> 9, r = gw & 511;
    int rl = rel[b * RR + r];     if (rl < 0 || rl > 45) rl = 0;
    int hd = head[b * RR + r]   & 255;
    int bh = behead[b * RR + r] & 255;
    const float* n1 = text_out + ((long)(b * SS + hd)) * H2;
    const float* n2 = text_out + ((long)(b * SS + bh)) * H2;
    float part = 0.f;
    for (int i = lane; i < H2; i += 64) {
        part += n1[i] * P[(long)i * 46 + rl];
        part += n2[i] * P[(long)(H2 + i) * 46 + rl];
    }
    for (int off = 32; off; off >>= 1) part += __shfl_down(part, off);
    if (lane == 0) {
        const float sc = 1.f / (1.f + expf(-(part + bil_b[0])));
        adj[((long)(b * SS + hd)) * SS + bh] = f2bf(sc);
        atomicAdd(&denom[b * SS + hd], sc);
    }
}

// ---------------- pooled attention + FC ----------------
__global__ __launch_bounds__(256) void k_attn(
    const float* __restrict__ text_out, const bf16* __restrict__ x2,
    const int* __restrict__ l0l1, const float* __restrict__ fcW,
    const float* __restrict__ fcb, float* __restrict__ out)
{
    const int b = blockIdx.x, tid = threadIdx.x;
    const int wave = tid >> 6, lane = tid & 63;
    __shared__ float xs[H2];
    __shared__ float sc[SS];
    __shared__ float red[16];
    const int l0 = l0l1[b * 2], l1 = l0l1[b * 2 + 1];
    for (int n = tid; n < H2; n += 256) {
        float s = 0.f;
        for (int i = l0; i <= l1 && i < SS; ++i) s += bf2f(x2[((long)(b * SS + i)) * H2 + n]);
        xs[n] = s;
    }
    __syncthreads();
    for (int j = wave; j < SS; j += 4) {
        const float* row = text_out + ((long)(b * SS + j)) * H2;
        float p = 0.f;
        for (int n = lane; n < H2; n += 64) p += xs[n] * row[n];
        for (int off = 32; off; off >>= 1) p += __shfl_down(p, off);
        if (lane == 0) sc[j] = p;
    }
    __syncthreads();
    const float v = sc[tid];
    float mx = v;
    for (int off = 32; off; off >>= 1) mx = fmaxf(mx, __shfl_down(mx, off));
    if (lane == 0) red[wave] = mx;
    __syncthreads();
    if (tid == 0) red[8] = fmaxf(fmaxf(red[0], red[1]), fmaxf(red[2], red[3]));
    __syncthreads();
    const float e = expf(v - red[8]);
    sc[tid] = e;
    float sm = e;
    for (int off = 32; off; off >>= 1) sm += __shfl_down(sm, off);
    if (lane == 0) red[wave] = sm;
    __syncthreads();
    if (tid == 0) red[9] = red[0] + red[1] + red[2] + red[3];
    __syncthreads();
    const float inv = 1.f / red[9];
    for (int n = tid; n < H2; n += 256) {
        float a = 0.f;
        for (int j = 0; j < SS; ++j) a += sc[j] * text_out[((long)(b * SS + j)) * H2 + n];
        xs[n] = a * inv;
    }
    __syncthreads();
    if (wave < 3) {
        float p = 0.f;
        for (int n = lane; n < H2; n += 64) p += xs[n] * fcW[n * 3 + wave];
        for (int off = 32; off; off >>= 1) p += __shfl_down(p, off);
        if (lane == 0) out[b * 3 + wave] = p + fcb[wave];
    }
}

extern "C" void kernel_launch(void* const* d_in, const int* in_sizes, int n_in,
                              void* d_out, int out_size, void* d_ws, size_t ws_size,
                              hipStream_t stream) {
    const int*   text_idx   = (const int*)d_in[0];
    const int*   aspect_idx = (const int*)d_in[1];
    const int*   left_idx   = (const int*)d_in[2];
    const int*   head       = (const int*)d_in[4];
    const int*   behead     = (const int*)d_in[5];
    const int*   rel        = (const int*)d_in[6];
    const float* embed      = (const float*)d_in[7];
    const float* relE       = (const float*)d_in[8];
    const float* Wf_ih      = (const float*)d_in[9];
    const float* Wf_hh      = (const float*)d_in[10];
    const float* bf_b       = (const float*)d_in[11];
    const float* Wb_ih      = (const float*)d_in[12];
    const float* Wb_hh      = (const float*)d_in[13];
    const float* bb_b       = (const float*)d_in[14];
    const float* bilW       = (const float*)d_in[15];
    const float* bilb       = (const float*)d_in[16];
    const float* gc1W       = (const float*)d_in[17];
    const float* gc1b       = (const float*)d_in[18];
    const float* gc2W       = (const float*)d_in[19];
    const float* gc2b       = (const float*)d_in[20];
    const float* fcW        = (const float*)d_in[21];
    const float* fcb        = (const float*)d_in[22];

    const bool  conc  = ws_size >= CONC_END;
    const size_t base2 = conc ? GATES_SZ : 0ul;

    char* ws = (char*)d_ws;
    bf16*  gatesF   = (bf16*)(ws);
    bf16*  gatesB   = conc ? (bf16*)(ws + GATES_SZ) : gatesF;
    bf16*  slot0bf  = (bf16*)(ws);                 // pw2/x2 (gates dead after LSTM)
    bf16*  slot1bf  = (bf16*)(ws + SLOTSZ);        // h1T/h2T
    float* text_out = (float*)(ws + OFF_TEXT  + base2);
    bf16*  adjw     = (bf16*)(ws + OFF_ADJ    + base2);
    float* P        = (float*)(ws + OFF_P     + base2);
    float* denom    = (float*)(ws + OFF_DENOM + base2);
    float* posw     = (float*)(ws + OFF_POSW  + base2);
    int*   l0l1     = (int*)(ws + OFF_L0L1    + base2);
    bf16*  W1T      = (bf16*)(ws + OFF_W1T    + base2);
    bf16*  W2T      = (bf16*)(ws + OFF_W2T    + base2);
    bf16*  hgbase   = (bf16*)(ws + OFF_HG     + base2);
    int*   flagbase = (int*)(ws + OFF_FLAGS   + base2);

    dim3 blk(256);

    hipMemsetAsync(adjw, 0, (size_t)BB * SS * SS * 2, stream);
    hipMemsetAsync(hgbase, 0, 155648 + 65536, stream);   // h buffers + flags
    k_lengths<<<64, blk, 0, stream>>>(text_idx, aspect_idx, left_idx, l0l1, posw, denom);
    k_P<<<(G4 * 46 + 255) / 256, blk, 0, stream>>>(bilW, relE, P);
    k_transpose2<<<(2 * H2 * H2 + 255) / 256, blk, 0, stream>>>(gc1W, gc2W, W1T, W2T);

    if (conc) {
        // merged gates GEMM: N=2400, routes gn<1200 -> gatesF, else gatesB
        gemm_bt<0, true, false, true, true, false><<<dim3(128, 19), blk, 0, stream>>>(
            embed, Wf_ih, Wb_ih, 16384, 2 * G4, EE, EE, EE, 0, 0,
            text_idx, bf_b, bb_b, nullptr, nullptr, nullptr, gatesF, gatesB, 0);
        k_lstm_mfma<<<2 * NWG, blk, 0, stream>>>(
            gatesF, gatesB, Wf_hh, Wb_hh, hgbase, flagbase, text_out, 0);
    } else {
        gemm_bt<0, true, false, true, true, false><<<dim3(128, 10), blk, 0, stream>>>(
            embed, Wf_ih, Wf_ih, 16384, G4, EE, EE, EE, 0, 0,
            text_idx, bf_b, bf_b, nullptr, nullptr, nullptr, gatesF, gatesF, 0);
        k_lstm_mfma<<<NWG, blk, 0, stream>>>(
            gatesF, gatesB, Wf_hh, Wb_hh, hgbase, flagbase, text_out, 0);
        gemm_bt<0, true, false, true, true, false><<<dim3(128, 10), blk, 0, stream>>>(
            embed, Wb_ih, Wb_ih, 16384, G4, EE, EE, EE, 0, 0,
            text_idx, bb_b, bb_b, nullptr, nullptr, nullptr, gatesB, gatesB, 0);
        k_lstm_mfma<<<NWG, blk, 0, stream>>>(
            gatesF, gatesB, Wf_hh, Wb_hh, hgbase, flagbase, text_out, 1);
    }

    k_scores<<<(BB * RR * 64 + 255) / 256, blk, 0, stream>>>(
        text_out, P, head, behead, rel, bilb, adjw, denom);

    // hidden1 = (posw*text_out) @ gc1_W  (A staged f32->bf16 with row scale; no pw1 pass)
    gemm_bt<1, false, false, true, false, true><<<dim3(128, 5), blk, 0, stream>>>(
        text_out, W1T, nullptr, 16384, H2, H2, H2, H2, 0, 0,
        nullptr, nullptr, nullptr, posw, nullptr, nullptr, slot1bf, nullptr, 0);
    // pw2 = posw * relu(adj@hidden1/denom + b1) -> slot0
    gemm_bt<2, false, true, false, false, false><<<dim3(2, 5, 64), blk, 0, stream>>>(
        adjw, slot1bf, nullptr, SS, H2, SS, SS, SS, (long)SS * SS, (long)H2 * SS,
        nullptr, gc1b, nullptr, nullptr, denom, posw, slot0bf, nullptr, H2);
    // hidden2 = pw2 @ gc2_W -> slot1
    gemm_bt<1, false, false, false, false, false><<<dim3(128, 5), blk, 0, stream>>>(
        slot0bf, W2T, nullptr, 16384, H2, H2, H2, H2, 0, 0,
        nullptr, nullptr, nullptr, nullptr, nullptr, nullptr, slot1bf, nullptr, 0);
    // x2 = relu(adj@hidden2/denom + b2) -> slot0 (bf16)
    gemm_bt<3, false, true, false, false, false><<<dim3(2, 5, 64), blk, 0, stream>>>(
        adjw, slot1bf, nullptr, SS, H2, SS, SS, SS, (long)SS * SS, (long)H2 * SS,
        nullptr, gc2b, nullptr, nullptr, denom, posw, slot0bf, nullptr, H2);

    k_attn<<<64, blk, 0, stream>>>(text_out, slot0bf, l0l1, fcW, fcb, (float*)d_out);
}